// Round 1
// baseline (961.188 us; speedup 1.0000x reference)
//
#include <hip/hip_runtime.h>
#include <math.h>

#define BB 512
#define SS 128
#define NROWS (BB*SS)      // 65536
#define TM 16
#define NBLK (NROWS/TM)    // 4096

__device__ __forceinline__ float leaky01(float x){ return x >= 0.f ? x : 0.1f*x; }

#define BN_INV 0.9999950000374997f
#define SELU_A 1.6732632423543772f
#define SELU_S 1.0507009873554805f

// ---------------- conv stack (tiny) ----------------
__global__ void conv1_kernel(const float* __restrict__ T, const float* __restrict__ w,
                             const float* __restrict__ bias, const float* __restrict__ g,
                             const float* __restrict__ bb, float* __restrict__ out)
{
    int t = blockIdx.x*blockDim.x + threadIdx.x;
    if (t >= 32*68*68) return;
    int oc  = t / (68*68);
    int rem = t % (68*68);
    int oy = rem / 68, ox = rem % 68;
    float acc = bias[oc];
    #pragma unroll
    for (int ky=0; ky<5; ++ky) {
        int iy = oy*2 - 1 + ky;
        if (iy < 0 || iy >= 138) continue;
        #pragma unroll
        for (int kx=0; kx<5; ++kx) {
            int ix = ox*2 - 1 + kx;
            if (ix < 0 || ix >= 138) continue;
            acc += w[oc*25 + ky*5 + kx] * T[iy*138 + ix];
        }
    }
    acc = acc * (g[oc]*BN_INV) + bb[oc];
    out[t] = leaky01(acc);
}

__global__ void conv2_kernel(const float* __restrict__ in, const float* __restrict__ w,
                             const float* __restrict__ bias, const float* __restrict__ g,
                             const float* __restrict__ bb, float* __restrict__ out)
{
    int t = blockIdx.x*blockDim.x + threadIdx.x;
    if (t >= 64*34*34) return;
    int oc  = t / 1156;
    int rem = t % 1156;
    int oy = rem / 34, ox = rem % 34;
    float acc = bias[oc];
    for (int ic=0; ic<32; ++ic) {
        #pragma unroll
        for (int ky=0; ky<4; ++ky) {
            int iy = oy*2 - 1 + ky;
            if (iy < 0 || iy >= 68) continue;
            #pragma unroll
            for (int kx=0; kx<4; ++kx) {
                int ix = ox*2 - 1 + kx;
                if (ix < 0 || ix >= 68) continue;
                acc += w[oc*512 + ic*16 + ky*4 + kx] * in[ic*4624 + iy*68 + ix];
            }
        }
    }
    acc = acc * (g[oc]*BN_INV) + bb[oc];
    out[t] = leaky01(acc);
}

__global__ void conv3_kernel(const float* __restrict__ in, const float* __restrict__ w,
                             const float* __restrict__ bias, const float* __restrict__ g,
                             const float* __restrict__ bb, float* __restrict__ out)
{
    int t = blockIdx.x*blockDim.x + threadIdx.x;
    if (t >= 128*289) return;
    int oc  = t / 289;
    int rem = t % 289;
    int oy = rem / 17, ox = rem % 17;
    float acc = bias[oc];
    for (int ic=0; ic<64; ++ic) {
        #pragma unroll
        for (int ky=0; ky<4; ++ky) {
            int iy = oy*2 - 1 + ky;
            if (iy < 0 || iy >= 34) continue;
            #pragma unroll
            for (int kx=0; kx<4; ++kx) {
                int ix = ox*2 - 1 + kx;
                if (ix < 0 || ix >= 34) continue;
                acc += w[oc*1024 + ic*16 + ky*4 + kx] * in[ic*1156 + iy*34 + ix];
            }
        }
    }
    acc = acc * (g[oc]*BN_INV) + bb[oc];
    out[t] = leaky01(acc);   // (128, 17, 17): out[oc*289 + oy*17 + ox]
}

// ---------------- c_mean / h2 / c2 (small) ----------------
__global__ void cmean_kernel(const float* __restrict__ t3, const int* __restrict__ lat,
                             const int* __restrict__ lon, float* __restrict__ cmean)
{
    int b = blockIdx.x;        // 512
    int d = threadIdx.x;       // 128
    float acc = 0.f;
    for (int k=0; k<64; ++k) {
        int p = lat[b*64+k]*17 + lon[b*64+k];
        acc += t3[d*289 + p];
    }
    cmean[b*128 + d] = acc * (1.f/64.f);
}

__global__ void h2_kernel(const float* __restrict__ cmean, const float* __restrict__ w,
                          const float* __restrict__ bias, float* __restrict__ out)
{
    int t = blockIdx.x*blockDim.x + threadIdx.x;
    if (t >= 512*256) return;
    int b = t / 256, n = t % 256;
    float acc = bias[n];
    for (int k=0; k<128; ++k) acc += cmean[b*128+k] * w[k*256+n];
    out[t] = acc > 0.f ? SELU_S*acc : SELU_S*SELU_A*(expf(acc)-1.f);
}

__global__ void c2_kernel(const float* __restrict__ h2, const float* __restrict__ w,
                          const float* __restrict__ bias, float* __restrict__ out)
{
    int t = blockIdx.x*blockDim.x + threadIdx.x;
    if (t >= 512*128) return;
    int b = t / 128, d = t % 128;
    float acc = bias[d];
    for (int k=0; k<256; ++k) acc += h2[b*256+k] * w[k*128+d];
    out[t] = acc;
}

// ---------------- fused per-row mega kernel ----------------
// per block: TM=16 rows.  x(156) -> h1(512,relu) -> rho(128) -> xcat(256) -> h3(512,relu) -> logm/logv
__global__ __launch_bounds__(256) void mega_kernel(
    const int* __restrict__ roads,
    const int* __restrict__ map_u, const int* __restrict__ map_s1,
    const int* __restrict__ map_s2, const int* __restrict__ map_s3,
    const float* __restrict__ emb_u, const float* __restrict__ emb_s1,
    const float* __restrict__ emb_s2, const float* __restrict__ emb_s3,
    const float* __restrict__ w1,  const float* __restrict__ b1,
    const float* __restrict__ w21, const float* __restrict__ b21,
    const float* __restrict__ c2,
    const float* __restrict__ fw1,  const float* __restrict__ fb1,
    const float* __restrict__ fw21, const float* __restrict__ fb21,
    const float* __restrict__ fw22, const float* __restrict__ fb22,
    float* __restrict__ logm, float* __restrict__ logv)
{
    __shared__ float xs[TM*156];     //  9984 B
    __shared__ float hbuf[TM*512];   // 32768 B
    __shared__ float xc[TM*256];     // 16384 B
    __shared__ float pm[TM*16];      //  1024 B
    __shared__ float pv[TM*16];      //  1024 B

    const int tid = threadIdx.x;
    const int r0 = blockIdx.x * TM;
    const int b  = r0 >> 7;          // 16 consecutive rows share one b (16 | 128)

    // ---- gather x rows ----
    for (int idx = tid; idx < TM*156; idx += 256) {
        int row = idx / 156;
        int k   = idx - row*156;
        int road = roads[r0 + row];
        float v;
        if (k < 128)      v = emb_u [map_u [road]*128 + k];
        else if (k < 144) v = emb_s1[map_s1[road]*16  + (k-128)];
        else if (k < 152) v = emb_s2[map_s2[road]*8   + (k-144)];
        else              v = emb_s3[map_s3[road]*4   + (k-152)];
        xs[idx] = v;
    }
    __syncthreads();

    // ---- GEMM1: h1 = relu(x @ w1 + b1)   K=156, N=512 ----
    {
        float acc0[TM], acc1[TM];
        #pragma unroll
        for (int row=0; row<TM; ++row) { acc0[row]=0.f; acc1[row]=0.f; }
        const int n0 = tid, n1 = tid + 256;
        for (int k=0; k<156; k+=4) {
            float wa0 = w1[(k+0)*512+n0], wb0 = w1[(k+0)*512+n1];
            float wa1 = w1[(k+1)*512+n0], wb1 = w1[(k+1)*512+n1];
            float wa2 = w1[(k+2)*512+n0], wb2 = w1[(k+2)*512+n1];
            float wa3 = w1[(k+3)*512+n0], wb3 = w1[(k+3)*512+n1];
            #pragma unroll
            for (int row=0; row<TM; ++row) {
                const float4 x4 = *(const float4*)&xs[row*156 + k];
                acc0[row] += x4.x*wa0 + x4.y*wa1 + x4.z*wa2 + x4.w*wa3;
                acc1[row] += x4.x*wb0 + x4.y*wb1 + x4.z*wb2 + x4.w*wb3;
            }
        }
        float bb0 = b1[n0], bb1 = b1[n1];
        #pragma unroll
        for (int row=0; row<TM; ++row) {
            hbuf[row*512+n0] = fmaxf(acc0[row]+bb0, 0.f);
            hbuf[row*512+n1] = fmaxf(acc1[row]+bb1, 0.f);
        }
    }
    __syncthreads();

    // ---- GEMM2: rho = h1 @ w21 + b21  -> xc[:,0:128]   K=512, N=128 ----
    {
        const int d  = tid & 127;
        const int rg = tid >> 7;           // 0/1, 8 rows each
        const int rbase = rg * (TM/2);
        float acc[TM/2];
        #pragma unroll
        for (int i=0;i<TM/2;++i) acc[i]=0.f;
        for (int n=0; n<512; n+=4) {
            float w0 = w21[(n+0)*128+d];
            float w1v= w21[(n+1)*128+d];
            float w2 = w21[(n+2)*128+d];
            float w3 = w21[(n+3)*128+d];
            #pragma unroll
            for (int i=0;i<TM/2;++i) {
                const float4 h4 = *(const float4*)&hbuf[(rbase+i)*512 + n];
                acc[i] += h4.x*w0 + h4.y*w1v + h4.z*w2 + h4.w*w3;
            }
        }
        float bbv = b21[d];
        #pragma unroll
        for (int i=0;i<TM/2;++i)
            xc[(rbase+i)*256 + d] = acc[i] + bbv;
    }
    // fill xc[:,128:256] = c2[b]  (disjoint region, no sync needed vs rho writes)
    for (int idx = tid; idx < TM*128; idx += 256) {
        int row = idx >> 7;
        int d   = idx & 127;
        xc[row*256 + 128 + d] = c2[b*128 + d];
    }
    __syncthreads();

    // ---- GEMM3: h3 = relu(xcat @ fw1 + fb1)   K=256, N=512 -> hbuf ----
    {
        float acc0[TM], acc1[TM];
        #pragma unroll
        for (int row=0; row<TM; ++row) { acc0[row]=0.f; acc1[row]=0.f; }
        const int n0 = tid, n1 = tid + 256;
        for (int k=0; k<256; k+=4) {
            float wa0 = fw1[(k+0)*512+n0], wb0 = fw1[(k+0)*512+n1];
            float wa1 = fw1[(k+1)*512+n0], wb1 = fw1[(k+1)*512+n1];
            float wa2 = fw1[(k+2)*512+n0], wb2 = fw1[(k+2)*512+n1];
            float wa3 = fw1[(k+3)*512+n0], wb3 = fw1[(k+3)*512+n1];
            #pragma unroll
            for (int row=0; row<TM; ++row) {
                const float4 x4 = *(const float4*)&xc[row*256 + k];
                acc0[row] += x4.x*wa0 + x4.y*wa1 + x4.z*wa2 + x4.w*wa3;
                acc1[row] += x4.x*wb0 + x4.y*wb1 + x4.z*wb2 + x4.w*wb3;
            }
        }
        float bb0 = fb1[n0], bb1 = fb1[n1];
        #pragma unroll
        for (int row=0; row<TM; ++row) {
            hbuf[row*512+n0] = fmaxf(acc0[row]+bb0, 0.f);
            hbuf[row*512+n1] = fmaxf(acc1[row]+bb1, 0.f);
        }
    }
    __syncthreads();

    // ---- dual dot with fw21 / fw22 -> logm/logv ----
    {
        int row = tid >> 4;
        int seg = tid & 15;
        float sm = 0.f, sv = 0.f;
        #pragma unroll 8
        for (int j=0; j<32; ++j) {
            int n = j*16 + seg;       // strided so LDS conflicts stay 4-way
            float h = hbuf[row*512 + n];
            sm += h * fw21[n];
            sv += h * fw22[n];
        }
        pm[row*16+seg] = sm;
        pv[row*16+seg] = sv;
    }
    __syncthreads();
    if (tid < TM) {
        float sm = 0.f, sv = 0.f;
        #pragma unroll
        for (int s=0; s<16; ++s) { sm += pm[tid*16+s]; sv += pv[tid*16+s]; }
        logm[r0+tid] = sm + fb21[0];
        logv[r0+tid] = sv + fb22[0];
    }
}

// ---------------- final per-trajectory reduction ----------------
__global__ __launch_bounds__(64) void final_kernel(
    const int* __restrict__ roads, const float* __restrict__ ratios,
    const float* __restrict__ lengths,
    const float* __restrict__ logm, const float* __restrict__ logv,
    float* __restrict__ out)
{
    int b = blockIdx.x;
    int lane = threadIdx.x;
    int i0 = b*128 + lane;
    int i1 = i0 + 64;
    float rl0 = lengths[roads[i0]] * ratios[i0];
    float rl1 = lengths[roads[i1]] * ratios[i1];

    float tsum = rl0 + rl1;
    #pragma unroll
    for (int off=32; off; off>>=1) tsum += __shfl_xor(tsum, off, 64);
    float l = tsum;
    float logl = logf(l);

    float lw0 = logf(rl0) - logl;
    float lw1 = logf(rl1) - logl;

    float am0 = logm[i0] + lw0, am1 = logm[i1] + lw1;
    float av0 = logv[i0] + 2.f*lw0, av1 = logv[i1] + 2.f*lw1;

    float mm = fmaxf(am0, am1);
    #pragma unroll
    for (int off=32; off; off>>=1) mm = fmaxf(mm, __shfl_xor(mm, off, 64));
    float se = expf(am0-mm) + expf(am1-mm);
    #pragma unroll
    for (int off=32; off; off>>=1) se += __shfl_xor(se, off, 64);
    float lsem = logf(se) + mm;

    float mv = fmaxf(av0, av1);
    #pragma unroll
    for (int off=32; off; off>>=1) mv = fmaxf(mv, __shfl_xor(mv, off, 64));
    float sev = expf(av0-mv) + expf(av1-mv);
    #pragma unroll
    for (int off=32; off; off>>=1) sev += __shfl_xor(sev, off, 64);
    float lsev = logf(sev) + mv;

    if (lane == 0) {
        out[b]       = logl - lsem;
        out[512 + b] = logl - 3.f*lsem - lsev;
    }
}

extern "C" void kernel_launch(void* const* d_in, const int* in_sizes, int n_in,
                              void* d_out, int out_size, void* d_ws, size_t ws_size,
                              hipStream_t stream) {
    const int*   roads   = (const int*)  d_in[0];
    const float* ratios  = (const float*)d_in[1];
    const float* T       = (const float*)d_in[2];
    const int*   lon_idx = (const int*)  d_in[3];
    const int*   lat_idx = (const int*)  d_in[4];
    const float* lengths = (const float*)d_in[5];
    const int*   map_u   = (const int*)  d_in[6];
    const int*   map_s1  = (const int*)  d_in[7];
    const int*   map_s2  = (const int*)  d_in[8];
    const int*   map_s3  = (const int*)  d_in[9];
    const float* emb_u   = (const float*)d_in[10];
    const float* emb_s1  = (const float*)d_in[11];
    const float* emb_s2  = (const float*)d_in[12];
    const float* emb_s3  = (const float*)d_in[13];
    const float* rho_w1  = (const float*)d_in[14];
    const float* rho_b1  = (const float*)d_in[15];
    const float* rho_w21 = (const float*)d_in[16];
    const float* rho_b21 = (const float*)d_in[17];
    const float* conv1_w = (const float*)d_in[18];
    const float* conv1_b = (const float*)d_in[19];
    const float* bn1_g   = (const float*)d_in[20];
    const float* bn1_b   = (const float*)d_in[21];
    const float* conv2_w = (const float*)d_in[22];
    const float* conv2_b = (const float*)d_in[23];
    const float* bn2_g   = (const float*)d_in[24];
    const float* bn2_b   = (const float*)d_in[25];
    const float* conv3_w = (const float*)d_in[26];
    const float* conv3_b = (const float*)d_in[27];
    const float* bn3_g   = (const float*)d_in[28];
    const float* bn3_b   = (const float*)d_in[29];
    const float* f2_w1   = (const float*)d_in[30];
    const float* f2_b1   = (const float*)d_in[31];
    const float* f2_w2   = (const float*)d_in[32];
    const float* f2_b2   = (const float*)d_in[33];
    const float* f_w1    = (const float*)d_in[34];
    const float* f_b1    = (const float*)d_in[35];
    const float* f_w21   = (const float*)d_in[36];
    const float* f_b21   = (const float*)d_in[37];
    const float* f_w22   = (const float*)d_in[38];
    const float* f_b22   = (const float*)d_in[39];

    float* ws    = (float*)d_ws;
    float* t1    = ws;              // 32*68*68  = 147968
    float* t2    = t1 + 147968;     // 64*34*34  =  73984
    float* t3    = t2 + 73984;      // 128*289   =  36992
    float* cmean = t3 + 36992;      // 512*128   =  65536
    float* h2b   = cmean + 65536;   // 512*256   = 131072
    float* c2b   = h2b + 131072;    // 512*128   =  65536
    float* logm  = c2b + 65536;     // 65536
    float* logv  = logm + 65536;    // 65536  -> total ~2.6 MB

    conv1_kernel<<<(32*68*68+255)/256, 256, 0, stream>>>(T, conv1_w, conv1_b, bn1_g, bn1_b, t1);
    conv2_kernel<<<(64*34*34+255)/256, 256, 0, stream>>>(t1, conv2_w, conv2_b, bn2_g, bn2_b, t2);
    conv3_kernel<<<(128*289+255)/256, 256, 0, stream>>>(t2, conv3_w, conv3_b, bn3_g, bn3_b, t3);
    cmean_kernel<<<512, 128, 0, stream>>>(t3, lat_idx, lon_idx, cmean);
    h2_kernel<<<(512*256+255)/256, 256, 0, stream>>>(cmean, f2_w1, f2_b1, h2b);
    c2_kernel<<<(512*128+255)/256, 256, 0, stream>>>(h2b, f2_w2, f2_b2, c2b);
    mega_kernel<<<NBLK, 256, 0, stream>>>(roads, map_u, map_s1, map_s2, map_s3,
                                          emb_u, emb_s1, emb_s2, emb_s3,
                                          rho_w1, rho_b1, rho_w21, rho_b21,
                                          c2b, f_w1, f_b1, f_w21, f_b21, f_w22, f_b22,
                                          logm, logv);
    final_kernel<<<512, 64, 0, stream>>>(roads, ratios, lengths, logm, logv, (float*)d_out);
}

// Round 2
// 364.101 us; speedup vs baseline: 2.6399x; 2.6399x over previous
//
#include <hip/hip_runtime.h>
#include <math.h>

#define BB 512
#define SS 128
#define NROWS (BB*SS)      // 65536
#define TM 32              // rows per block
#define NBLK (NROWS/TM)    // 2048

__device__ __forceinline__ float leaky01(float x){ return x >= 0.f ? x : 0.1f*x; }

#define BN_INV 0.9999950000374997f
#define SELU_A 1.6732632423543772f
#define SELU_S 1.0507009873554805f

typedef __attribute__((ext_vector_type(8))) short short8;
typedef __attribute__((ext_vector_type(4))) float f32x4;

__device__ __forceinline__ unsigned short f2bf(float f) {
    unsigned int u = __float_as_uint(f);
    u += 0x7fff + ((u >> 16) & 1);          // round-to-nearest-even
    return (unsigned short)(u >> 16);
}
__device__ __forceinline__ uint2 pack4bf(float a, float b, float c, float d) {
    uint2 r;
    r.x = (unsigned int)f2bf(a) | ((unsigned int)f2bf(b) << 16);
    r.y = (unsigned int)f2bf(c) | ((unsigned int)f2bf(d) << 16);
    return r;
}

// ---------------- weight prep: fp32 -> bf16 transposed/padded ----------------
// w1t   [512][160]  (w1 is [156][512], pad K 156->160 with zeros)
// w21t  [128][512]  (w21 is [512][128])
// fw1t  [512][256]  (fw1 is [256][512])
__global__ void prep_weights(const float* __restrict__ w1, const float* __restrict__ w21,
                             const float* __restrict__ fw1,
                             unsigned short* __restrict__ w1t, unsigned short* __restrict__ w21t,
                             unsigned short* __restrict__ fw1t)
{
    int t = blockIdx.x*blockDim.x + threadIdx.x;
    if (t < 512*160) {
        int n = t / 160, k = t % 160;
        float v = (k < 156) ? w1[k*512 + n] : 0.f;
        w1t[t] = f2bf(v);
    } else if (t < 512*160 + 128*512) {
        int i = t - 512*160;
        int d = i / 512, k = i % 512;
        w21t[i] = f2bf(w21[k*128 + d]);
    } else if (t < 512*160 + 128*512 + 512*256) {
        int i = t - (512*160 + 128*512);
        int n = i / 256, k = i % 256;
        fw1t[i] = f2bf(fw1[k*512 + n]);
    }
}

// ---------------- conv stack (tiny) ----------------
__global__ void conv1_kernel(const float* __restrict__ T, const float* __restrict__ w,
                             const float* __restrict__ bias, const float* __restrict__ g,
                             const float* __restrict__ bb, float* __restrict__ out)
{
    int t = blockIdx.x*blockDim.x + threadIdx.x;
    if (t >= 32*68*68) return;
    int oc  = t / (68*68);
    int rem = t % (68*68);
    int oy = rem / 68, ox = rem % 68;
    float acc = bias[oc];
    #pragma unroll
    for (int ky=0; ky<5; ++ky) {
        int iy = oy*2 - 1 + ky;
        if (iy < 0 || iy >= 138) continue;
        #pragma unroll
        for (int kx=0; kx<5; ++kx) {
            int ix = ox*2 - 1 + kx;
            if (ix < 0 || ix >= 138) continue;
            acc += w[oc*25 + ky*5 + kx] * T[iy*138 + ix];
        }
    }
    acc = acc * (g[oc]*BN_INV) + bb[oc];
    out[t] = leaky01(acc);
}

__global__ void conv2_kernel(const float* __restrict__ in, const float* __restrict__ w,
                             const float* __restrict__ bias, const float* __restrict__ g,
                             const float* __restrict__ bb, float* __restrict__ out)
{
    int t = blockIdx.x*blockDim.x + threadIdx.x;
    if (t >= 64*34*34) return;
    int oc  = t / 1156;
    int rem = t % 1156;
    int oy = rem / 34, ox = rem % 34;
    float acc = bias[oc];
    for (int ic=0; ic<32; ++ic) {
        #pragma unroll
        for (int ky=0; ky<4; ++ky) {
            int iy = oy*2 - 1 + ky;
            if (iy < 0 || iy >= 68) continue;
            #pragma unroll
            for (int kx=0; kx<4; ++kx) {
                int ix = ox*2 - 1 + kx;
                if (ix < 0 || ix >= 68) continue;
                acc += w[oc*512 + ic*16 + ky*4 + kx] * in[ic*4624 + iy*68 + ix];
            }
        }
    }
    acc = acc * (g[oc]*BN_INV) + bb[oc];
    out[t] = leaky01(acc);
}

__global__ void conv3_kernel(const float* __restrict__ in, const float* __restrict__ w,
                             const float* __restrict__ bias, const float* __restrict__ g,
                             const float* __restrict__ bb, float* __restrict__ out)
{
    int t = blockIdx.x*blockDim.x + threadIdx.x;
    if (t >= 128*289) return;
    int oc  = t / 289;
    int rem = t % 289;
    int oy = rem / 17, ox = rem % 17;
    float acc = bias[oc];
    for (int ic=0; ic<64; ++ic) {
        #pragma unroll
        for (int ky=0; ky<4; ++ky) {
            int iy = oy*2 - 1 + ky;
            if (iy < 0 || iy >= 34) continue;
            #pragma unroll
            for (int kx=0; kx<4; ++kx) {
                int ix = ox*2 - 1 + kx;
                if (ix < 0 || ix >= 34) continue;
                acc += w[oc*1024 + ic*16 + ky*4 + kx] * in[ic*1156 + iy*34 + ix];
            }
        }
    }
    acc = acc * (g[oc]*BN_INV) + bb[oc];
    out[t] = leaky01(acc);   // (128, 17, 17)
}

// ---------------- c_mean / h2 / c2 (small) ----------------
__global__ void cmean_kernel(const float* __restrict__ t3, const int* __restrict__ lat,
                             const int* __restrict__ lon, float* __restrict__ cmean)
{
    int b = blockIdx.x;
    int d = threadIdx.x;
    float acc = 0.f;
    for (int k=0; k<64; ++k) {
        int p = lat[b*64+k]*17 + lon[b*64+k];
        acc += t3[d*289 + p];
    }
    cmean[b*128 + d] = acc * (1.f/64.f);
}

__global__ void h2_kernel(const float* __restrict__ cmean, const float* __restrict__ w,
                          const float* __restrict__ bias, float* __restrict__ out)
{
    int t = blockIdx.x*blockDim.x + threadIdx.x;
    if (t >= 512*256) return;
    int b = t / 256, n = t % 256;
    float acc = bias[n];
    for (int k=0; k<128; ++k) acc += cmean[b*128+k] * w[k*256+n];
    out[t] = acc > 0.f ? SELU_S*acc : SELU_S*SELU_A*(expf(acc)-1.f);
}

__global__ void c2_kernel(const float* __restrict__ h2, const float* __restrict__ w,
                          const float* __restrict__ bias, float* __restrict__ out)
{
    int t = blockIdx.x*blockDim.x + threadIdx.x;
    if (t >= 512*128) return;
    int b = t / 128, d = t % 128;
    float acc = bias[d];
    for (int k=0; k<256; ++k) acc += h2[b*256+k] * w[k*128+d];
    out[t] = acc;
}

// ---------------- fused per-row mega kernel (MFMA bf16) ----------------
// Per block: 32 rows. Chain x(160)->h1(512)->rho(128)+c2->xcat(256)->h3(512)->2 dots.
// Every GEMM computed as D = W^T (A) x X^T (B); output fragment writes row-major
// activation [32][K] back to LDS with 8B stores (k-contiguous per lane).
#define XS_S 168
#define H1_S 520
#define XC_S 264

__global__ __launch_bounds__(256) void mega_kernel(
    const int* __restrict__ roads,
    const int* __restrict__ map_u, const int* __restrict__ map_s1,
    const int* __restrict__ map_s2, const int* __restrict__ map_s3,
    const float* __restrict__ emb_u, const float* __restrict__ emb_s1,
    const float* __restrict__ emb_s2, const float* __restrict__ emb_s3,
    const unsigned short* __restrict__ w1t, const float* __restrict__ b1,
    const unsigned short* __restrict__ w21t, const float* __restrict__ b21,
    const float* __restrict__ c2,
    const unsigned short* __restrict__ fw1t, const float* __restrict__ fb1,
    const float* __restrict__ fw21, const float* __restrict__ fb21,
    const float* __restrict__ fw22, const float* __restrict__ fb22,
    float* __restrict__ logm, float* __restrict__ logv)
{
    __shared__ unsigned short h1s[32*H1_S];   // 33280 B
    __shared__ unsigned short xcs[32*XC_S];   // 16896 B  (aliased as xs first)
    __shared__ float pm[4][32];
    __shared__ float pv[4][32];
    unsigned short* xs = xcs;                 // [32][XS_S] during stage 1

    const int tid  = threadIdx.x;
    const int wid  = tid >> 6;
    const int lane = tid & 63;
    const int lo   = lane & 15;
    const int hi   = lane >> 4;
    const int r0   = blockIdx.x * TM;
    const int b    = r0 >> 7;

    // ---- gather x rows (row-major bf16 [32][XS_S]) ----
    {
        int row = tid >> 3, seg = tid & 7;
        int road = roads[r0 + row];
        const float* src = emb_u + (long)map_u[road]*128 + seg*16;
        #pragma unroll
        for (int i=0;i<4;++i) {
            float4 v = *(const float4*)&src[i*4];
            *(uint2*)&xs[row*XS_S + seg*16 + i*4] = pack4bf(v.x, v.y, v.z, v.w);
        }
    }
    for (int idx = tid; idx < 32*32; idx += 256) {
        int row = idx >> 5, k2 = idx & 31;
        int road = roads[r0 + row];
        float v;
        if      (k2 < 16) v = emb_s1[map_s1[road]*16 + k2];
        else if (k2 < 24) v = emb_s2[map_s2[road]*8  + (k2-16)];
        else if (k2 < 28) v = emb_s3[map_s3[road]*4  + (k2-24)];
        else              v = 0.f;
        xs[row*XS_S + 128 + k2] = f2bf(v);
    }
    __syncthreads();

    const int n0 = wid * 128;   // wave's N_out base for GEMM1/GEMM3

    // ---- GEMM1: h1^T = w1t x xs^T   (Nout=512, K=160) ----
    {
        f32x4 acc[8][2];
        #pragma unroll
        for (int mt=0;mt<8;++mt){ acc[mt][0]=(f32x4)(0.f); acc[mt][1]=(f32x4)(0.f); }
        for (int ks=0; ks<5; ++ks) {
            const int kb = ks*32 + hi*8;
            short8 bf0 = *(const short8*)&xs[lo*XS_S + kb];
            short8 bf1 = *(const short8*)&xs[(16+lo)*XS_S + kb];
            short8 af[8];
            #pragma unroll
            for (int mt=0;mt<8;++mt)
                af[mt] = *(const short8*)&w1t[(n0 + mt*16 + lo)*160 + kb];
            #pragma unroll
            for (int mt=0;mt<8;++mt) {
                acc[mt][0] = __builtin_amdgcn_mfma_f32_16x16x32_bf16(af[mt], bf0, acc[mt][0], 0,0,0);
                acc[mt][1] = __builtin_amdgcn_mfma_f32_16x16x32_bf16(af[mt], bf1, acc[mt][1], 0,0,0);
            }
        }
        #pragma unroll
        for (int mt=0;mt<8;++mt) {
            const int nb = n0 + mt*16 + hi*4;
            float4 bias = *(const float4*)&b1[nb];
            const float* bp = (const float*)&bias;
            #pragma unroll
            for (int nt=0;nt<2;++nt) {
                const float* a = (const float*)&acc[mt][nt];
                float y0 = fmaxf(a[0]+bp[0], 0.f), y1 = fmaxf(a[1]+bp[1], 0.f);
                float y2 = fmaxf(a[2]+bp[2], 0.f), y3 = fmaxf(a[3]+bp[3], 0.f);
                *(uint2*)&h1s[(nt*16+lo)*H1_S + nb] = pack4bf(y0,y1,y2,y3);
            }
        }
    }
    __syncthreads();

    // ---- GEMM2: rho^T = w21t x h1^T  (Nout=128, K=512) -> xcat[:,0:128] ----
    {
        const int n02 = wid * 32;
        f32x4 acc[2][2];
        acc[0][0]=(f32x4)(0.f); acc[0][1]=(f32x4)(0.f);
        acc[1][0]=(f32x4)(0.f); acc[1][1]=(f32x4)(0.f);
        for (int ks=0; ks<16; ++ks) {
            const int kb = ks*32 + hi*8;
            short8 bf0 = *(const short8*)&h1s[lo*H1_S + kb];
            short8 bf1 = *(const short8*)&h1s[(16+lo)*H1_S + kb];
            short8 a0 = *(const short8*)&w21t[(n02 + lo)*512 + kb];
            short8 a1 = *(const short8*)&w21t[(n02 + 16 + lo)*512 + kb];
            acc[0][0] = __builtin_amdgcn_mfma_f32_16x16x32_bf16(a0, bf0, acc[0][0], 0,0,0);
            acc[0][1] = __builtin_amdgcn_mfma_f32_16x16x32_bf16(a0, bf1, acc[0][1], 0,0,0);
            acc[1][0] = __builtin_amdgcn_mfma_f32_16x16x32_bf16(a1, bf0, acc[1][0], 0,0,0);
            acc[1][1] = __builtin_amdgcn_mfma_f32_16x16x32_bf16(a1, bf1, acc[1][1], 0,0,0);
        }
        #pragma unroll
        for (int mt=0;mt<2;++mt) {
            const int nb = n02 + mt*16 + hi*4;
            float4 bias = *(const float4*)&b21[nb];
            const float* bp = (const float*)&bias;
            #pragma unroll
            for (int nt=0;nt<2;++nt) {
                const float* a = (const float*)&acc[mt][nt];
                *(uint2*)&xcs[(nt*16+lo)*XC_S + nb] =
                    pack4bf(a[0]+bp[0], a[1]+bp[1], a[2]+bp[2], a[3]+bp[3]);
            }
        }
    }
    // xcat[:,128:256] = c2[b]  (xs region is dead now; xcs writes race nothing)
    {
        int row = tid >> 3, seg = tid & 7;
        const float* src = c2 + b*128 + seg*16;
        #pragma unroll
        for (int i=0;i<4;++i) {
            float4 v = *(const float4*)&src[i*4];
            *(uint2*)&xcs[row*XC_S + 128 + seg*16 + i*4] = pack4bf(v.x, v.y, v.z, v.w);
        }
    }
    __syncthreads();

    // ---- GEMM3: h3^T = fw1t x xcat^T (Nout=512, K=256) + fused dual dot ----
    {
        f32x4 acc[8][2];
        #pragma unroll
        for (int mt=0;mt<8;++mt){ acc[mt][0]=(f32x4)(0.f); acc[mt][1]=(f32x4)(0.f); }
        for (int ks=0; ks<8; ++ks) {
            const int kb = ks*32 + hi*8;
            short8 bf0 = *(const short8*)&xcs[lo*XC_S + kb];
            short8 bf1 = *(const short8*)&xcs[(16+lo)*XC_S + kb];
            short8 af[8];
            #pragma unroll
            for (int mt=0;mt<8;++mt)
                af[mt] = *(const short8*)&fw1t[(n0 + mt*16 + lo)*256 + kb];
            #pragma unroll
            for (int mt=0;mt<8;++mt) {
                acc[mt][0] = __builtin_amdgcn_mfma_f32_16x16x32_bf16(af[mt], bf0, acc[mt][0], 0,0,0);
                acc[mt][1] = __builtin_amdgcn_mfma_f32_16x16x32_bf16(af[mt], bf1, acc[mt][1], 0,0,0);
            }
        }
        float sm0=0.f, sm1=0.f, sv0=0.f, sv1=0.f;
        #pragma unroll
        for (int mt=0;mt<8;++mt) {
            const int nb = n0 + mt*16 + hi*4;
            float4 bias = *(const float4*)&fb1[nb];
            float4 wm   = *(const float4*)&fw21[nb];
            float4 wv   = *(const float4*)&fw22[nb];
            const float *bp=(const float*)&bias, *wmp=(const float*)&wm, *wvp=(const float*)&wv;
            const float* a0 = (const float*)&acc[mt][0];
            const float* a1 = (const float*)&acc[mt][1];
            #pragma unroll
            for (int j=0;j<4;++j) {
                float y0 = fmaxf(a0[j]+bp[j], 0.f);
                float y1 = fmaxf(a1[j]+bp[j], 0.f);
                sm0 += y0*wmp[j]; sv0 += y0*wvp[j];
                sm1 += y1*wmp[j]; sv1 += y1*wvp[j];
            }
        }
        // reduce over hi groups (lanes xor 16, 32)
        sm0 += __shfl_xor(sm0, 16, 64); sm0 += __shfl_xor(sm0, 32, 64);
        sm1 += __shfl_xor(sm1, 16, 64); sm1 += __shfl_xor(sm1, 32, 64);
        sv0 += __shfl_xor(sv0, 16, 64); sv0 += __shfl_xor(sv0, 32, 64);
        sv1 += __shfl_xor(sv1, 16, 64); sv1 += __shfl_xor(sv1, 32, 64);
        if (hi == 0) {
            pm[wid][lo] = sm0; pm[wid][16+lo] = sm1;
            pv[wid][lo] = sv0; pv[wid][16+lo] = sv1;
        }
    }
    __syncthreads();
    if (tid < 32) {
        float sm = pm[0][tid]+pm[1][tid]+pm[2][tid]+pm[3][tid];
        float sv = pv[0][tid]+pv[1][tid]+pv[2][tid]+pv[3][tid];
        logm[r0+tid] = sm + fb21[0];
        logv[r0+tid] = sv + fb22[0];
    }
}

// ---------------- final per-trajectory reduction ----------------
__global__ __launch_bounds__(64) void final_kernel(
    const int* __restrict__ roads, const float* __restrict__ ratios,
    const float* __restrict__ lengths,
    const float* __restrict__ logm, const float* __restrict__ logv,
    float* __restrict__ out)
{
    int b = blockIdx.x;
    int lane = threadIdx.x;
    int i0 = b*128 + lane;
    int i1 = i0 + 64;
    float rl0 = lengths[roads[i0]] * ratios[i0];
    float rl1 = lengths[roads[i1]] * ratios[i1];

    float tsum = rl0 + rl1;
    #pragma unroll
    for (int off=32; off; off>>=1) tsum += __shfl_xor(tsum, off, 64);
    float l = tsum;
    float logl = logf(l);

    float lw0 = logf(rl0) - logl;
    float lw1 = logf(rl1) - logl;

    float am0 = logm[i0] + lw0, am1 = logm[i1] + lw1;
    float av0 = logv[i0] + 2.f*lw0, av1 = logv[i1] + 2.f*lw1;

    float mm = fmaxf(am0, am1);
    #pragma unroll
    for (int off=32; off; off>>=1) mm = fmaxf(mm, __shfl_xor(mm, off, 64));
    float se = expf(am0-mm) + expf(am1-mm);
    #pragma unroll
    for (int off=32; off; off>>=1) se += __shfl_xor(se, off, 64);
    float lsem = logf(se) + mm;

    float mv = fmaxf(av0, av1);
    #pragma unroll
    for (int off=32; off; off>>=1) mv = fmaxf(mv, __shfl_xor(mv, off, 64));
    float sev = expf(av0-mv) + expf(av1-mv);
    #pragma unroll
    for (int off=32; off; off>>=1) sev += __shfl_xor(sev, off, 64);
    float lsev = logf(sev) + mv;

    if (lane == 0) {
        out[b]       = logl - lsem;
        out[512 + b] = logl - 3.f*lsem - lsev;
    }
}

extern "C" void kernel_launch(void* const* d_in, const int* in_sizes, int n_in,
                              void* d_out, int out_size, void* d_ws, size_t ws_size,
                              hipStream_t stream) {
    const int*   roads   = (const int*)  d_in[0];
    const float* ratios  = (const float*)d_in[1];
    const float* T       = (const float*)d_in[2];
    const int*   lon_idx = (const int*)  d_in[3];
    const int*   lat_idx = (const int*)  d_in[4];
    const float* lengths = (const float*)d_in[5];
    const int*   map_u   = (const int*)  d_in[6];
    const int*   map_s1  = (const int*)  d_in[7];
    const int*   map_s2  = (const int*)  d_in[8];
    const int*   map_s3  = (const int*)  d_in[9];
    const float* emb_u   = (const float*)d_in[10];
    const float* emb_s1  = (const float*)d_in[11];
    const float* emb_s2  = (const float*)d_in[12];
    const float* emb_s3  = (const float*)d_in[13];
    const float* rho_w1  = (const float*)d_in[14];
    const float* rho_b1  = (const float*)d_in[15];
    const float* rho_w21 = (const float*)d_in[16];
    const float* rho_b21 = (const float*)d_in[17];
    const float* conv1_w = (const float*)d_in[18];
    const float* conv1_b = (const float*)d_in[19];
    const float* bn1_g   = (const float*)d_in[20];
    const float* bn1_b   = (const float*)d_in[21];
    const float* conv2_w = (const float*)d_in[22];
    const float* conv2_b = (const float*)d_in[23];
    const float* bn2_g   = (const float*)d_in[24];
    const float* bn2_b   = (const float*)d_in[25];
    const float* conv3_w = (const float*)d_in[26];
    const float* conv3_b = (const float*)d_in[27];
    const float* bn3_g   = (const float*)d_in[28];
    const float* bn3_b   = (const float*)d_in[29];
    const float* f2_w1   = (const float*)d_in[30];
    const float* f2_b1   = (const float*)d_in[31];
    const float* f2_w2   = (const float*)d_in[32];
    const float* f2_b2   = (const float*)d_in[33];
    const float* f_w1    = (const float*)d_in[34];
    const float* f_b1    = (const float*)d_in[35];
    const float* f_w21   = (const float*)d_in[36];
    const float* f_b21   = (const float*)d_in[37];
    const float* f_w22   = (const float*)d_in[38];
    const float* f_b22   = (const float*)d_in[39];

    float* ws    = (float*)d_ws;
    float* t1    = ws;              // 32*68*68  = 147968
    float* t2    = t1 + 147968;     // 64*34*34  =  73984
    float* t3    = t2 + 73984;      // 128*289   =  36992
    float* cmean = t3 + 36992;      // 512*128
    float* h2b   = cmean + 65536;   // 512*256
    float* c2b   = h2b + 131072;    // 512*128
    float* logm  = c2b + 65536;     // 65536
    float* logv  = logm + 65536;    // 65536
    unsigned short* w1t  = (unsigned short*)(logv + 65536);  // 512*160
    unsigned short* w21t = w1t + 512*160;                    // 128*512
    unsigned short* fw1t = w21t + 128*512;                   // 512*256

    prep_weights<<<(512*160 + 128*512 + 512*256 + 255)/256, 256, 0, stream>>>(
        rho_w1, rho_w21, f_w1, w1t, w21t, fw1t);
    conv1_kernel<<<(32*68*68+255)/256, 256, 0, stream>>>(T, conv1_w, conv1_b, bn1_g, bn1_b, t1);
    conv2_kernel<<<(64*34*34+255)/256, 256, 0, stream>>>(t1, conv2_w, conv2_b, bn2_g, bn2_b, t2);
    conv3_kernel<<<(128*289+255)/256, 256, 0, stream>>>(t2, conv3_w, conv3_b, bn3_g, bn3_b, t3);
    cmean_kernel<<<512, 128, 0, stream>>>(t3, lat_idx, lon_idx, cmean);
    h2_kernel<<<(512*256+255)/256, 256, 0, stream>>>(cmean, f2_w1, f2_b1, h2b);
    c2_kernel<<<(512*128+255)/256, 256, 0, stream>>>(h2b, f2_w2, f2_b2, c2b);
    mega_kernel<<<NBLK, 256, 0, stream>>>(roads, map_u, map_s1, map_s2, map_s3,
                                          emb_u, emb_s1, emb_s2, emb_s3,
                                          w1t, rho_b1, w21t, rho_b21,
                                          c2b, fw1t, f_b1, f_w21, f_b21, f_w22, f_b22,
                                          logm, logv);
    final_kernel<<<512, 64, 0, stream>>>(roads, ratios, lengths, logm, logv, (float*)d_out);
}

// Round 3
// 218.982 us; speedup vs baseline: 4.3893x; 1.6627x over previous
//
#include <hip/hip_runtime.h>
#include <math.h>

#define BB 512
#define SS 128
#define NROWS (BB*SS)      // 65536
#define TM 32              // rows per block
#define NBLK (NROWS/TM)    // 2048

__device__ __forceinline__ float leaky01(float x){ return x >= 0.f ? x : 0.1f*x; }

#define BN_INV 0.9999950000374997f
#define SELU_A 1.6732632423543772f
#define SELU_S 1.0507009873554805f

typedef __attribute__((ext_vector_type(8))) short short8;
typedef __attribute__((ext_vector_type(4))) float f32x4;

__device__ __forceinline__ unsigned short f2bf(float f) {
    unsigned int u = __float_as_uint(f);
    u += 0x7fff + ((u >> 16) & 1);          // round-to-nearest-even
    return (unsigned short)(u >> 16);
}
__device__ __forceinline__ uint2 pack4bf(float a, float b, float c, float d) {
    uint2 r;
    r.x = (unsigned int)f2bf(a) | ((unsigned int)f2bf(b) << 16);
    r.y = (unsigned int)f2bf(c) | ((unsigned int)f2bf(d) << 16);
    return r;
}

// ================= combo: weight swizzle-prep + conv1 =================
// Swizzled fragment layout: for each (ntile of 16 N-rows, ks of K=32 step),
// a 64-lane x 16B block: entry[lane][j] = W[k = ks*32+(lane>>4)*8+j][n = ntile*16+(lane&15)]
// so mega's A-fragment load is base + lane*16B (coalesced 1KB per wave).
#define PREP_BLOCKS 1088   // (81920+65536+131072)/256
#define CONV1_BLOCKS 578   // 32*68*68/256 rounded up

__global__ __launch_bounds__(256) void combo1_kernel(
    const float* __restrict__ w1, const float* __restrict__ w21, const float* __restrict__ fw1,
    unsigned short* __restrict__ sw1, unsigned short* __restrict__ sw21, unsigned short* __restrict__ sw3,
    const float* __restrict__ T, const float* __restrict__ cw,
    const float* __restrict__ cbias, const float* __restrict__ g,
    const float* __restrict__ bb, float* __restrict__ out)
{
    if (blockIdx.x < PREP_BLOCKS) {
        int t = blockIdx.x*256 + threadIdx.x;
        if (t < 81920) {                       // sw1: 32 ntiles x 5 ks   (w1 [156][512], pad->160)
            int j = t & 7; int r = t >> 3; int lane = r & 63; r >>= 6;
            int ks = r % 5; int nt = r / 5;
            int n = nt*16 + (lane & 15);
            int k = ks*32 + (lane >> 4)*8 + j;
            float v = (k < 156) ? w1[k*512 + n] : 0.f;
            sw1[t] = f2bf(v);
        } else if (t < 147456) {               // sw21: 8 ntiles x 16 ks  (w21 [512][128])
            int u = t - 81920;
            int j = u & 7; int r = u >> 3; int lane = r & 63; r >>= 6;
            int ks = r & 15; int nt = r >> 4;
            int d = nt*16 + (lane & 15);
            int k = ks*32 + (lane >> 4)*8 + j;
            sw21[u] = f2bf(w21[k*128 + d]);
        } else if (t < 278528) {               // sw3: 32 ntiles x 8 ks   (fw1 [256][512])
            int u = t - 147456;
            int j = u & 7; int r = u >> 3; int lane = r & 63; r >>= 6;
            int ks = r & 7; int nt = r >> 3;
            int n = nt*16 + (lane & 15);
            int k = ks*32 + (lane >> 4)*8 + j;
            sw3[u] = f2bf(fw1[k*512 + n]);
        }
    } else {
        int t = (blockIdx.x - PREP_BLOCKS)*256 + threadIdx.x;
        if (t >= 32*68*68) return;
        int oc  = t / (68*68);
        int rem = t % (68*68);
        int oy = rem / 68, ox = rem % 68;
        float acc = cbias[oc];
        #pragma unroll
        for (int ky=0; ky<5; ++ky) {
            int iy = oy*2 - 1 + ky;
            if (iy < 0 || iy >= 138) continue;
            #pragma unroll
            for (int kx=0; kx<5; ++kx) {
                int ix = ox*2 - 1 + kx;
                if (ix < 0 || ix >= 138) continue;
                acc += cw[oc*25 + ky*5 + kx] * T[iy*138 + ix];
            }
        }
        acc = acc * (g[oc]*BN_INV) + bb[oc];
        out[t] = leaky01(acc);
    }
}

// ================= conv2: 4 lanes per output (8 ic each) =================
__global__ __launch_bounds__(256) void conv2_kernel(
    const float* __restrict__ in, const float* __restrict__ w,
    const float* __restrict__ bias, const float* __restrict__ g,
    const float* __restrict__ bb, float* __restrict__ out)
{
    int gid = blockIdx.x*256 + threadIdx.x;
    if (gid >= 64*34*34*4) return;
    int o   = gid >> 2;
    int icg = gid & 3;
    int oc  = o / 1156;
    int rem = o % 1156;
    int oy = rem / 34, ox = rem % 34;
    float acc = 0.f;
    #pragma unroll
    for (int ii=0; ii<8; ++ii) {
        int ic = icg*8 + ii;
        #pragma unroll
        for (int ky=0; ky<4; ++ky) {
            int iy = oy*2 - 1 + ky;
            if (iy < 0 || iy >= 68) continue;
            #pragma unroll
            for (int kx=0; kx<4; ++kx) {
                int ix = ox*2 - 1 + kx;
                if (ix < 0 || ix >= 68) continue;
                acc += w[oc*512 + ic*16 + ky*4 + kx] * in[ic*4624 + iy*68 + ix];
            }
        }
    }
    acc += __shfl_xor(acc, 1, 64);
    acc += __shfl_xor(acc, 2, 64);
    if (icg == 0) {
        acc = (acc + bias[oc]) * (g[oc]*BN_INV) + bb[oc];
        out[o] = leaky01(acc);
    }
}

// ================= conv3: 8 lanes per output (8 ic each), transposed out =================
__global__ __launch_bounds__(256) void conv3_kernel(
    const float* __restrict__ in, const float* __restrict__ w,
    const float* __restrict__ bias, const float* __restrict__ g,
    const float* __restrict__ bb, float* __restrict__ outT)   // outT[pos*128 + oc]
{
    int gid = blockIdx.x*256 + threadIdx.x;
    if (gid >= 128*289*8) return;
    int o   = gid >> 3;
    int icg = gid & 7;
    int oc  = o / 289;
    int rem = o % 289;
    int oy = rem / 17, ox = rem % 17;
    float acc = 0.f;
    #pragma unroll
    for (int ii=0; ii<8; ++ii) {
        int ic = icg*8 + ii;
        #pragma unroll
        for (int ky=0; ky<4; ++ky) {
            int iy = oy*2 - 1 + ky;
            if (iy < 0 || iy >= 34) continue;
            #pragma unroll
            for (int kx=0; kx<4; ++kx) {
                int ix = ox*2 - 1 + kx;
                if (ix < 0 || ix >= 34) continue;
                acc += w[oc*1024 + ic*16 + ky*4 + kx] * in[ic*1156 + iy*34 + ix];
            }
        }
    }
    acc += __shfl_xor(acc, 1, 64);
    acc += __shfl_xor(acc, 2, 64);
    acc += __shfl_xor(acc, 4, 64);
    if (icg == 0) {
        acc = (acc + bias[oc]) * (g[oc]*BN_INV) + bb[oc];
        outT[rem*128 + oc] = leaky01(acc);
    }
}

// ================= fused cmean -> h2(selu) -> c2, one block per b =================
__global__ __launch_bounds__(256) void cmh2c2_kernel(
    const float* __restrict__ t3T, const int* __restrict__ lat, const int* __restrict__ lon,
    const float* __restrict__ w1, const float* __restrict__ b1,
    const float* __restrict__ w2, const float* __restrict__ b2,
    float* __restrict__ c2b)
{
    __shared__ int   ps[64];
    __shared__ float part[256];
    __shared__ float cms[128];
    __shared__ float h2s[256];
    const int b = blockIdx.x;
    const int tid = threadIdx.x;
    if (tid < 64) ps[tid] = lat[b*64+tid]*17 + lon[b*64+tid];
    __syncthreads();
    // cmean: 2 halves of k per d
    {
        int d = tid & 127, half = tid >> 7;
        float s = 0.f;
        #pragma unroll 8
        for (int k=0; k<32; ++k) s += t3T[ps[half*32+k]*128 + d];
        part[tid] = s;
    }
    __syncthreads();
    if (tid < 128) cms[tid] = (part[tid] + part[tid+128]) * (1.f/64.f);
    __syncthreads();
    // h2 = selu(cms @ w1 + b1)
    {
        float acc = b1[tid];
        #pragma unroll 8
        for (int k=0; k<128; ++k) acc += cms[k] * w1[k*256 + tid];
        h2s[tid] = acc > 0.f ? SELU_S*acc : SELU_S*SELU_A*(expf(acc)-1.f);
    }
    __syncthreads();
    // c2 = h2s @ w2 + b2
    {
        int d = tid & 127, half = tid >> 7;
        float acc = 0.f;
        #pragma unroll 8
        for (int k=0; k<128; ++k) acc += h2s[half*128 + k] * w2[(half*128+k)*128 + d];
        part[tid] = acc;
    }
    __syncthreads();
    if (tid < 128) c2b[b*128 + tid] = part[tid] + part[tid+128] + b2[tid];
}

// ================= fused per-row mega kernel (MFMA bf16, swizzled weights) =================
#define XS_S 168
#define H1_S 520
#define XC_S 264

__global__ __launch_bounds__(256) void mega_kernel(
    const int* __restrict__ roads,
    const int* __restrict__ map_u, const int* __restrict__ map_s1,
    const int* __restrict__ map_s2, const int* __restrict__ map_s3,
    const float* __restrict__ emb_u, const float* __restrict__ emb_s1,
    const float* __restrict__ emb_s2, const float* __restrict__ emb_s3,
    const unsigned short* __restrict__ sw1, const float* __restrict__ b1,
    const unsigned short* __restrict__ sw21, const float* __restrict__ b21,
    const float* __restrict__ c2,
    const unsigned short* __restrict__ sw3, const float* __restrict__ fb1,
    const float* __restrict__ fw21, const float* __restrict__ fb21,
    const float* __restrict__ fw22, const float* __restrict__ fb22,
    float* __restrict__ logm, float* __restrict__ logv)
{
    __shared__ unsigned short h1s[32*H1_S];   // 33280 B
    __shared__ unsigned short xcs[32*XC_S];   // 16896 B  (aliased as xs first)
    __shared__ float pm[4][32];
    __shared__ float pv[4][32];
    unsigned short* xs = xcs;                 // [32][XS_S] during stage 1

    const int tid  = threadIdx.x;
    const int wid  = tid >> 6;
    const int lane = tid & 63;
    const int lo   = lane & 15;
    const int hi   = lane >> 4;
    const int r0   = blockIdx.x * TM;
    const int b    = r0 >> 7;

    // ---- prefetch GEMM1 ks=0 A-fragments (coalesced lane*16B); drains at the barrier ----
    short8 afp[8];
    #pragma unroll
    for (int mt=0;mt<8;++mt)
        afp[mt] = *(const short8*)&sw1[((wid*8+mt)*5 + 0)*512 + lane*8];

    // ---- gather x rows (row-major bf16 [32][XS_S]) ----
    {
        int row = tid >> 3, seg = tid & 7;
        int road = roads[r0 + row];
        const float* src = emb_u + (long)map_u[road]*128 + seg*16;
        #pragma unroll
        for (int i=0;i<4;++i) {
            float4 v = *(const float4*)&src[i*4];
            *(uint2*)&xs[row*XS_S + seg*16 + i*4] = pack4bf(v.x, v.y, v.z, v.w);
        }
    }
    for (int idx = tid; idx < 32*32; idx += 256) {
        int row = idx >> 5, k2 = idx & 31;
        int road = roads[r0 + row];
        float v;
        if      (k2 < 16) v = emb_s1[map_s1[road]*16 + k2];
        else if (k2 < 24) v = emb_s2[map_s2[road]*8  + (k2-16)];
        else if (k2 < 28) v = emb_s3[map_s3[road]*4  + (k2-24)];
        else              v = 0.f;
        xs[row*XS_S + 128 + k2] = f2bf(v);
    }
    __syncthreads();

    // ---- GEMM1: h1^T = W1 x X^T   (Nout=512, K=160) ----
    short8 a2p0, a2p1;     // GEMM2 ks=0 prefetch
    {
        f32x4 acc[8][2];
        #pragma unroll
        for (int mt=0;mt<8;++mt){ acc[mt][0]=(f32x4)(0.f); acc[mt][1]=(f32x4)(0.f); }
        // ks = 0 from prefetch
        {
            short8 bf0 = *(const short8*)&xs[lo*XS_S + hi*8];
            short8 bf1 = *(const short8*)&xs[(16+lo)*XS_S + hi*8];
            #pragma unroll
            for (int mt=0;mt<8;++mt) {
                acc[mt][0] = __builtin_amdgcn_mfma_f32_16x16x32_bf16(afp[mt], bf0, acc[mt][0], 0,0,0);
                acc[mt][1] = __builtin_amdgcn_mfma_f32_16x16x32_bf16(afp[mt], bf1, acc[mt][1], 0,0,0);
            }
        }
        #pragma unroll
        for (int ks=1; ks<5; ++ks) {
            const int kb = ks*32 + hi*8;
            short8 bf0 = *(const short8*)&xs[lo*XS_S + kb];
            short8 bf1 = *(const short8*)&xs[(16+lo)*XS_S + kb];
            short8 af[8];
            #pragma unroll
            for (int mt=0;mt<8;++mt)
                af[mt] = *(const short8*)&sw1[((wid*8+mt)*5 + ks)*512 + lane*8];
            #pragma unroll
            for (int mt=0;mt<8;++mt) {
                acc[mt][0] = __builtin_amdgcn_mfma_f32_16x16x32_bf16(af[mt], bf0, acc[mt][0], 0,0,0);
                acc[mt][1] = __builtin_amdgcn_mfma_f32_16x16x32_bf16(af[mt], bf1, acc[mt][1], 0,0,0);
            }
        }
        // prefetch GEMM2 ks=0 while epilogue runs
        a2p0 = *(const short8*)&sw21[((wid*2+0)*16 + 0)*512 + lane*8];
        a2p1 = *(const short8*)&sw21[((wid*2+1)*16 + 0)*512 + lane*8];
        const int n0 = wid * 128;
        #pragma unroll
        for (int mt=0;mt<8;++mt) {
            const int nb = n0 + mt*16 + hi*4;
            float4 bias = *(const float4*)&b1[nb];
            const float* bp = (const float*)&bias;
            #pragma unroll
            for (int nt=0;nt<2;++nt) {
                const float* a = (const float*)&acc[mt][nt];
                float y0 = fmaxf(a[0]+bp[0], 0.f), y1 = fmaxf(a[1]+bp[1], 0.f);
                float y2 = fmaxf(a[2]+bp[2], 0.f), y3 = fmaxf(a[3]+bp[3], 0.f);
                *(uint2*)&h1s[(nt*16+lo)*H1_S + nb] = pack4bf(y0,y1,y2,y3);
            }
        }
    }
    __syncthreads();

    // ---- GEMM2: rho^T = W21 x h1^T  (Nout=128, K=512) -> xcat[:,0:128] ----
    short8 a3p[8];         // GEMM3 ks=0 prefetch
    {
        const int n02 = wid * 32;
        f32x4 acc[2][2];
        acc[0][0]=(f32x4)(0.f); acc[0][1]=(f32x4)(0.f);
        acc[1][0]=(f32x4)(0.f); acc[1][1]=(f32x4)(0.f);
        // ks=0 from prefetch
        {
            short8 bf0 = *(const short8*)&h1s[lo*H1_S + hi*8];
            short8 bf1 = *(const short8*)&h1s[(16+lo)*H1_S + hi*8];
            acc[0][0] = __builtin_amdgcn_mfma_f32_16x16x32_bf16(a2p0, bf0, acc[0][0], 0,0,0);
            acc[0][1] = __builtin_amdgcn_mfma_f32_16x16x32_bf16(a2p0, bf1, acc[0][1], 0,0,0);
            acc[1][0] = __builtin_amdgcn_mfma_f32_16x16x32_bf16(a2p1, bf0, acc[1][0], 0,0,0);
            acc[1][1] = __builtin_amdgcn_mfma_f32_16x16x32_bf16(a2p1, bf1, acc[1][1], 0,0,0);
        }
        #pragma unroll 5
        for (int ks=1; ks<16; ++ks) {
            const int kb = ks*32 + hi*8;
            short8 bf0 = *(const short8*)&h1s[lo*H1_S + kb];
            short8 bf1 = *(const short8*)&h1s[(16+lo)*H1_S + kb];
            short8 a0 = *(const short8*)&sw21[((wid*2+0)*16 + ks)*512 + lane*8];
            short8 a1 = *(const short8*)&sw21[((wid*2+1)*16 + ks)*512 + lane*8];
            acc[0][0] = __builtin_amdgcn_mfma_f32_16x16x32_bf16(a0, bf0, acc[0][0], 0,0,0);
            acc[0][1] = __builtin_amdgcn_mfma_f32_16x16x32_bf16(a0, bf1, acc[0][1], 0,0,0);
            acc[1][0] = __builtin_amdgcn_mfma_f32_16x16x32_bf16(a1, bf0, acc[1][0], 0,0,0);
            acc[1][1] = __builtin_amdgcn_mfma_f32_16x16x32_bf16(a1, bf1, acc[1][1], 0,0,0);
        }
        // prefetch GEMM3 ks=0
        #pragma unroll
        for (int mt=0;mt<8;++mt)
            a3p[mt] = *(const short8*)&sw3[((wid*8+mt)*8 + 0)*512 + lane*8];
        #pragma unroll
        for (int mt=0;mt<2;++mt) {
            const int nb = n02 + mt*16 + hi*4;
            float4 bias = *(const float4*)&b21[nb];
            const float* bp = (const float*)&bias;
            #pragma unroll
            for (int nt=0;nt<2;++nt) {
                const float* a = (const float*)&acc[mt][nt];
                *(uint2*)&xcs[(nt*16+lo)*XC_S + nb] =
                    pack4bf(a[0]+bp[0], a[1]+bp[1], a[2]+bp[2], a[3]+bp[3]);
            }
        }
    }
    // xcat[:,128:256] = c2[b]
    {
        int row = tid >> 3, seg = tid & 7;
        const float* src = c2 + b*128 + seg*16;
        #pragma unroll
        for (int i=0;i<4;++i) {
            float4 v = *(const float4*)&src[i*4];
            *(uint2*)&xcs[row*XC_S + 128 + seg*16 + i*4] = pack4bf(v.x, v.y, v.z, v.w);
        }
    }
    __syncthreads();

    // ---- GEMM3: h3^T = FW1 x xcat^T (Nout=512, K=256) + fused dual dot ----
    {
        const int n0 = wid * 128;
        f32x4 acc[8][2];
        #pragma unroll
        for (int mt=0;mt<8;++mt){ acc[mt][0]=(f32x4)(0.f); acc[mt][1]=(f32x4)(0.f); }
        {
            short8 bf0 = *(const short8*)&xcs[lo*XC_S + hi*8];
            short8 bf1 = *(const short8*)&xcs[(16+lo)*XC_S + hi*8];
            #pragma unroll
            for (int mt=0;mt<8;++mt) {
                acc[mt][0] = __builtin_amdgcn_mfma_f32_16x16x32_bf16(a3p[mt], bf0, acc[mt][0], 0,0,0);
                acc[mt][1] = __builtin_amdgcn_mfma_f32_16x16x32_bf16(a3p[mt], bf1, acc[mt][1], 0,0,0);
            }
        }
        #pragma unroll 3
        for (int ks=1; ks<8; ++ks) {
            const int kb = ks*32 + hi*8;
            short8 bf0 = *(const short8*)&xcs[lo*XC_S + kb];
            short8 bf1 = *(const short8*)&xcs[(16+lo)*XC_S + kb];
            short8 af[8];
            #pragma unroll
            for (int mt=0;mt<8;++mt)
                af[mt] = *(const short8*)&sw3[((wid*8+mt)*8 + ks)*512 + lane*8];
            #pragma unroll
            for (int mt=0;mt<8;++mt) {
                acc[mt][0] = __builtin_amdgcn_mfma_f32_16x16x32_bf16(af[mt], bf0, acc[mt][0], 0,0,0);
                acc[mt][1] = __builtin_amdgcn_mfma_f32_16x16x32_bf16(af[mt], bf1, acc[mt][1], 0,0,0);
            }
        }
        float sm0=0.f, sm1=0.f, sv0=0.f, sv1=0.f;
        #pragma unroll
        for (int mt=0;mt<8;++mt) {
            const int nb = n0 + mt*16 + hi*4;
            float4 bias = *(const float4*)&fb1[nb];
            float4 wm   = *(const float4*)&fw21[nb];
            float4 wv   = *(const float4*)&fw22[nb];
            const float *bp=(const float*)&bias, *wmp=(const float*)&wm, *wvp=(const float*)&wv;
            const float* a0 = (const float*)&acc[mt][0];
            const float* a1 = (const float*)&acc[mt][1];
            #pragma unroll
            for (int j=0;j<4;++j) {
                float y0 = fmaxf(a0[j]+bp[j], 0.f);
                float y1 = fmaxf(a1[j]+bp[j], 0.f);
                sm0 += y0*wmp[j]; sv0 += y0*wvp[j];
                sm1 += y1*wmp[j]; sv1 += y1*wvp[j];
            }
        }
        sm0 += __shfl_xor(sm0, 16, 64); sm0 += __shfl_xor(sm0, 32, 64);
        sm1 += __shfl_xor(sm1, 16, 64); sm1 += __shfl_xor(sm1, 32, 64);
        sv0 += __shfl_xor(sv0, 16, 64); sv0 += __shfl_xor(sv0, 32, 64);
        sv1 += __shfl_xor(sv1, 16, 64); sv1 += __shfl_xor(sv1, 32, 64);
        if (hi == 0) {
            pm[wid][lo] = sm0; pm[wid][16+lo] = sm1;
            pv[wid][lo] = sv0; pv[wid][16+lo] = sv1;
        }
    }
    __syncthreads();
    if (tid < 32) {
        float sm = pm[0][tid]+pm[1][tid]+pm[2][tid]+pm[3][tid];
        float sv = pv[0][tid]+pv[1][tid]+pv[2][tid]+pv[3][tid];
        logm[r0+tid] = sm + fb21[0];
        logv[r0+tid] = sv + fb22[0];
    }
}

// ================= final per-trajectory reduction =================
__global__ __launch_bounds__(64) void final_kernel(
    const int* __restrict__ roads, const float* __restrict__ ratios,
    const float* __restrict__ lengths,
    const float* __restrict__ logm, const float* __restrict__ logv,
    float* __restrict__ out)
{
    int b = blockIdx.x;
    int lane = threadIdx.x;
    int i0 = b*128 + lane;
    int i1 = i0 + 64;
    float rl0 = lengths[roads[i0]] * ratios[i0];
    float rl1 = lengths[roads[i1]] * ratios[i1];

    float tsum = rl0 + rl1;
    #pragma unroll
    for (int off=32; off; off>>=1) tsum += __shfl_xor(tsum, off, 64);
    float l = tsum;
    float logl = logf(l);

    float lw0 = logf(rl0) - logl;
    float lw1 = logf(rl1) - logl;

    float am0 = logm[i0] + lw0, am1 = logm[i1] + lw1;
    float av0 = logv[i0] + 2.f*lw0, av1 = logv[i1] + 2.f*lw1;

    float mm = fmaxf(am0, am1);
    #pragma unroll
    for (int off=32; off; off>>=1) mm = fmaxf(mm, __shfl_xor(mm, off, 64));
    float se = expf(am0-mm) + expf(am1-mm);
    #pragma unroll
    for (int off=32; off; off>>=1) se += __shfl_xor(se, off, 64);
    float lsem = logf(se) + mm;

    float mv = fmaxf(av0, av1);
    #pragma unroll
    for (int off=32; off; off>>=1) mv = fmaxf(mv, __shfl_xor(mv, off, 64));
    float sev = expf(av0-mv) + expf(av1-mv);
    #pragma unroll
    for (int off=32; off; off>>=1) sev += __shfl_xor(sev, off, 64);
    float lsev = logf(sev) + mv;

    if (lane == 0) {
        out[b]       = logl - lsem;
        out[512 + b] = logl - 3.f*lsem - lsev;
    }
}

extern "C" void kernel_launch(void* const* d_in, const int* in_sizes, int n_in,
                              void* d_out, int out_size, void* d_ws, size_t ws_size,
                              hipStream_t stream) {
    const int*   roads   = (const int*)  d_in[0];
    const float* ratios  = (const float*)d_in[1];
    const float* T       = (const float*)d_in[2];
    const int*   lon_idx = (const int*)  d_in[3];
    const int*   lat_idx = (const int*)  d_in[4];
    const float* lengths = (const float*)d_in[5];
    const int*   map_u   = (const int*)  d_in[6];
    const int*   map_s1  = (const int*)  d_in[7];
    const int*   map_s2  = (const int*)  d_in[8];
    const int*   map_s3  = (const int*)  d_in[9];
    const float* emb_u   = (const float*)d_in[10];
    const float* emb_s1  = (const float*)d_in[11];
    const float* emb_s2  = (const float*)d_in[12];
    const float* emb_s3  = (const float*)d_in[13];
    const float* rho_w1  = (const float*)d_in[14];
    const float* rho_b1  = (const float*)d_in[15];
    const float* rho_w21 = (const float*)d_in[16];
    const float* rho_b21 = (const float*)d_in[17];
    const float* conv1_w = (const float*)d_in[18];
    const float* conv1_b = (const float*)d_in[19];
    const float* bn1_g   = (const float*)d_in[20];
    const float* bn1_b   = (const float*)d_in[21];
    const float* conv2_w = (const float*)d_in[22];
    const float* conv2_b = (const float*)d_in[23];
    const float* bn2_g   = (const float*)d_in[24];
    const float* bn2_b   = (const float*)d_in[25];
    const float* conv3_w = (const float*)d_in[26];
    const float* conv3_b = (const float*)d_in[27];
    const float* bn3_g   = (const float*)d_in[28];
    const float* bn3_b   = (const float*)d_in[29];
    const float* f2_w1   = (const float*)d_in[30];
    const float* f2_b1   = (const float*)d_in[31];
    const float* f2_w2   = (const float*)d_in[32];
    const float* f2_b2   = (const float*)d_in[33];
    const float* f_w1    = (const float*)d_in[34];
    const float* f_b1    = (const float*)d_in[35];
    const float* f_w21   = (const float*)d_in[36];
    const float* f_b21   = (const float*)d_in[37];
    const float* f_w22   = (const float*)d_in[38];
    const float* f_b22   = (const float*)d_in[39];

    float* ws    = (float*)d_ws;
    float* t1    = ws;              // 32*68*68  = 147968
    float* t2    = t1 + 147968;     // 64*34*34  =  73984
    float* t3T   = t2 + 73984;      // 289*128   =  36992  (transposed)
    float* c2b   = t3T + 36992;     // 512*128
    float* logm  = c2b + 65536;     // 65536
    float* logv  = logm + 65536;    // 65536
    unsigned short* sw1  = (unsigned short*)(logv + 65536);  // 81920
    unsigned short* sw21 = sw1 + 81920;                      // 65536
    unsigned short* sw3  = sw21 + 65536;                     // 131072

    combo1_kernel<<<PREP_BLOCKS + CONV1_BLOCKS, 256, 0, stream>>>(
        rho_w1, rho_w21, f_w1, sw1, sw21, sw3,
        T, conv1_w, conv1_b, bn1_g, bn1_b, t1);
    conv2_kernel<<<(64*34*34*4 + 255)/256, 256, 0, stream>>>(t1, conv2_w, conv2_b, bn2_g, bn2_b, t2);
    conv3_kernel<<<(128*289*8 + 255)/256, 256, 0, stream>>>(t2, conv3_w, conv3_b, bn3_g, bn3_b, t3T);
    cmh2c2_kernel<<<512, 256, 0, stream>>>(t3T, lat_idx, lon_idx, f2_w1, f2_b1, f2_w2, f2_b2, c2b);
    mega_kernel<<<NBLK, 256, 0, stream>>>(roads, map_u, map_s1, map_s2, map_s3,
                                          emb_u, emb_s1, emb_s2, emb_s3,
                                          sw1, rho_b1, sw21, rho_b21,
                                          c2b, sw3, f_b1, f_w21, f_b21, f_w22, f_b22,
                                          logm, logv);
    final_kernel<<<512, 64, 0, stream>>>(roads, ratios, lengths, logm, logv, (float*)d_out);
}

// Round 4
// 124.213 us; speedup vs baseline: 7.7383x; 1.7630x over previous
//
#include <hip/hip_runtime.h>
#include <math.h>

#define BB 512
#define SS 128
#define NROWS (BB*SS)      // 65536
#define TM 32              // rows per block
#define NBLK (NROWS/TM)    // 2048

__device__ __forceinline__ float leaky01(float x){ return x >= 0.f ? x : 0.1f*x; }

#define BN_INV 0.9999950000374997f
#define SELU_A 1.6732632423543772f
#define SELU_S 1.0507009873554805f

typedef __attribute__((ext_vector_type(8))) short short8;
typedef __attribute__((ext_vector_type(4))) float f32x4;

__device__ __forceinline__ unsigned short f2bf(float f) {
    unsigned int u = __float_as_uint(f);
    u += 0x7fff + ((u >> 16) & 1);          // round-to-nearest-even
    return (unsigned short)(u >> 16);
}
__device__ __forceinline__ uint2 pack4bf(float a, float b, float c, float d) {
    uint2 r;
    r.x = (unsigned int)f2bf(a) | ((unsigned int)f2bf(b) << 16);
    r.y = (unsigned int)f2bf(c) | ((unsigned int)f2bf(d) << 16);
    return r;
}

// ================= combo: weight swizzle-prep + conv1 =================
// MFMA fragment layout: for each (ntile of 16 N-rows, ks of K=32 step),
// a 64-lane x 16B block: entry[lane][j] = W[k = ks*32+(lane>>4)*8+j][n = ntile*16+(lane&15)]
// Also: conv2/conv3 weights re-laid to [oc][ky*4+kx][ic] (channels-last inner).
#define PREP_N (278528 + 32768 + 131072)   // 442368
#define PREP_BLOCKS (PREP_N/256)           // 1728
#define CONV1_BLOCKS 578                   // ceil(147968/256)

__global__ __launch_bounds__(256) void combo1_kernel(
    const float* __restrict__ w1, const float* __restrict__ w21, const float* __restrict__ fw1,
    unsigned short* __restrict__ sw1, unsigned short* __restrict__ sw21, unsigned short* __restrict__ sw3,
    const float* __restrict__ c2w_in, const float* __restrict__ c3w_in,
    float* __restrict__ w2t, float* __restrict__ w3t,
    const float* __restrict__ T, const float* __restrict__ cw,
    const float* __restrict__ cbias, const float* __restrict__ g,
    const float* __restrict__ bb, float* __restrict__ out)   // out: t1 channels-last [pos68][32]
{
    if (blockIdx.x < PREP_BLOCKS) {
        int t = blockIdx.x*256 + threadIdx.x;
        if (t < 81920) {                       // sw1: 32 ntiles x 5 ks   (w1 [156][512], pad->160)
            int j = t & 7; int r = t >> 3; int lane = r & 63; r >>= 6;
            int ks = r % 5; int nt = r / 5;
            int n = nt*16 + (lane & 15);
            int k = ks*32 + (lane >> 4)*8 + j;
            float v = (k < 156) ? w1[k*512 + n] : 0.f;
            sw1[t] = f2bf(v);
        } else if (t < 147456) {               // sw21: 8 ntiles x 16 ks  (w21 [512][128])
            int u = t - 81920;
            int j = u & 7; int r = u >> 3; int lane = r & 63; r >>= 6;
            int ks = r & 15; int nt = r >> 4;
            int d = nt*16 + (lane & 15);
            int k = ks*32 + (lane >> 4)*8 + j;
            sw21[u] = f2bf(w21[k*128 + d]);
        } else if (t < 278528) {               // sw3: 32 ntiles x 8 ks   (fw1 [256][512])
            int u = t - 147456;
            int j = u & 7; int r = u >> 3; int lane = r & 63; r >>= 6;
            int ks = r & 7; int nt = r >> 3;
            int n = nt*16 + (lane & 15);
            int k = ks*32 + (lane >> 4)*8 + j;
            sw3[u] = f2bf(fw1[k*512 + n]);
        } else if (t < 278528 + 32768) {       // w2t[oc][kk][ic]  (conv2_w [oc][ic][kk16])
            int u = t - 278528;
            int oc = u >> 9; int r = u & 511;
            int kk = r >> 5; int ic = r & 31;
            w2t[u] = c2w_in[oc*512 + ic*16 + kk];
        } else {                               // w3t[oc][kk][ic]  (conv3_w [oc][ic][kk16])
            int u = t - (278528 + 32768);
            int oc = u >> 10; int r = u & 1023;
            int kk = r >> 6; int ic = r & 63;
            w3t[u] = c3w_in[oc*1024 + ic*16 + kk];
        }
    } else {
        int t = (blockIdx.x - PREP_BLOCKS)*256 + threadIdx.x;
        if (t >= 32*68*68) return;
        int oc  = t & 31;
        int pos = t >> 5;          // oy*68+ox
        int oy = pos / 68, ox = pos % 68;
        float acc = cbias[oc];
        #pragma unroll
        for (int ky=0; ky<5; ++ky) {
            int iy = oy*2 - 1 + ky;
            if (iy < 0 || iy >= 138) continue;
            #pragma unroll
            for (int kx=0; kx<5; ++kx) {
                int ix = ox*2 - 1 + kx;
                if (ix < 0 || ix >= 138) continue;
                acc += cw[oc*25 + ky*5 + kx] * T[iy*138 + ix];
            }
        }
        acc = acc * (g[oc]*BN_INV) + bb[oc];
        out[pos*32 + oc] = leaky01(acc);
    }
}

// ================= conv2: channels-last, 4 lanes per output (8 ic each) =================
__global__ __launch_bounds__(256) void conv2_kernel(
    const float* __restrict__ in,      // [pos68][32]
    const float* __restrict__ w2t,     // [oc][kk][ic32]
    const float* __restrict__ bias, const float* __restrict__ g,
    const float* __restrict__ bb, float* __restrict__ out)   // [pos34][64]
{
    int gid = blockIdx.x*256 + threadIdx.x;
    if (gid >= 64*34*34*4) return;
    int icg = gid & 3;
    int o   = gid >> 2;
    int oc  = o & 63;
    int pos = o >> 6;
    int oy = pos / 34, ox = pos % 34;
    float acc = 0.f;
    #pragma unroll
    for (int ky=0; ky<4; ++ky) {
        int iy = oy*2 - 1 + ky;
        if (iy < 0 || iy >= 68) continue;
        #pragma unroll
        for (int kx=0; kx<4; ++kx) {
            int ix = ox*2 - 1 + kx;
            if (ix < 0 || ix >= 68) continue;
            const float* ip = &in[(iy*68+ix)*32 + icg*8];
            const float* wp = &w2t[oc*512 + (ky*4+kx)*32 + icg*8];
            float4 i0 = *(const float4*)ip, i1 = *(const float4*)(ip+4);
            float4 w0 = *(const float4*)wp, w1v = *(const float4*)(wp+4);
            acc += i0.x*w0.x + i0.y*w0.y + i0.z*w0.z + i0.w*w0.w
                 + i1.x*w1v.x + i1.y*w1v.y + i1.z*w1v.z + i1.w*w1v.w;
        }
    }
    acc += __shfl_xor(acc, 1, 64);
    acc += __shfl_xor(acc, 2, 64);
    if (icg == 0) {
        acc = (acc + bias[oc]) * (g[oc]*BN_INV) + bb[oc];
        out[pos*64 + oc] = leaky01(acc);
    }
}

// ================= conv3: channels-last, 8 lanes per output, transposed out =================
__global__ __launch_bounds__(256) void conv3_kernel(
    const float* __restrict__ in,      // [pos34][64]
    const float* __restrict__ w3t,     // [oc][kk][ic64]
    const float* __restrict__ bias, const float* __restrict__ g,
    const float* __restrict__ bb, float* __restrict__ outT)  // [pos17][128]
{
    int gid = blockIdx.x*256 + threadIdx.x;
    if (gid >= 128*289*8) return;
    int icg = gid & 7;
    int o   = gid >> 3;
    int oc  = o & 127;
    int pos = o >> 7;
    int oy = pos / 17, ox = pos % 17;
    float acc = 0.f;
    #pragma unroll
    for (int ky=0; ky<4; ++ky) {
        int iy = oy*2 - 1 + ky;
        if (iy < 0 || iy >= 34) continue;
        #pragma unroll
        for (int kx=0; kx<4; ++kx) {
            int ix = ox*2 - 1 + kx;
            if (ix < 0 || ix >= 34) continue;
            const float* ip = &in[(iy*34+ix)*64 + icg*8];
            const float* wp = &w3t[oc*1024 + (ky*4+kx)*64 + icg*8];
            float4 i0 = *(const float4*)ip, i1 = *(const float4*)(ip+4);
            float4 w0 = *(const float4*)wp, w1v = *(const float4*)(wp+4);
            acc += i0.x*w0.x + i0.y*w0.y + i0.z*w0.z + i0.w*w0.w
                 + i1.x*w1v.x + i1.y*w1v.y + i1.z*w1v.z + i1.w*w1v.w;
        }
    }
    acc += __shfl_xor(acc, 1, 64);
    acc += __shfl_xor(acc, 2, 64);
    acc += __shfl_xor(acc, 4, 64);
    if (icg == 0) {
        acc = (acc + bias[oc]) * (g[oc]*BN_INV) + bb[oc];
        outT[pos*128 + oc] = leaky01(acc);
    }
}

// ================= fused cmean -> h2(selu) -> c2, one block per b =================
__global__ __launch_bounds__(256) void cmh2c2_kernel(
    const float* __restrict__ t3T, const int* __restrict__ lat, const int* __restrict__ lon,
    const float* __restrict__ w1, const float* __restrict__ b1,
    const float* __restrict__ w2, const float* __restrict__ b2,
    float* __restrict__ c2b)
{
    __shared__ int   ps[64];
    __shared__ float part[256];
    __shared__ float cms[128];
    __shared__ float h2s[256];
    const int b = blockIdx.x;
    const int tid = threadIdx.x;
    if (tid < 64) ps[tid] = lat[b*64+tid]*17 + lon[b*64+tid];
    __syncthreads();
    {
        int d = tid & 127, half = tid >> 7;
        float s = 0.f;
        #pragma unroll 8
        for (int k=0; k<32; ++k) s += t3T[ps[half*32+k]*128 + d];
        part[tid] = s;
    }
    __syncthreads();
    if (tid < 128) cms[tid] = (part[tid] + part[tid+128]) * (1.f/64.f);
    __syncthreads();
    {
        float acc = b1[tid];
        #pragma unroll 8
        for (int k=0; k<128; ++k) acc += cms[k] * w1[k*256 + tid];
        h2s[tid] = acc > 0.f ? SELU_S*acc : SELU_S*SELU_A*(expf(acc)-1.f);
    }
    __syncthreads();
    {
        int d = tid & 127, half = tid >> 7;
        float acc = 0.f;
        #pragma unroll 8
        for (int k=0; k<128; ++k) acc += h2s[half*128 + k] * w2[(half*128+k)*128 + d];
        part[tid] = acc;
    }
    __syncthreads();
    if (tid < 128) c2b[b*128 + tid] = part[tid] + part[tid+128] + b2[tid];
}

// ================= fused per-row mega kernel (MFMA bf16, aliased LDS) =================
// Single 33.3KB LDS region reused across phases (xs -> h1s -> xcs+pm/pv),
// with barriers separating each read-phase from the overwrite.
#define XS_S 168
#define H1_S 520
#define XC_S 264

__global__ __launch_bounds__(256, 4) void mega_kernel(
    const int* __restrict__ roads,
    const int* __restrict__ map_u, const int* __restrict__ map_s1,
    const int* __restrict__ map_s2, const int* __restrict__ map_s3,
    const float* __restrict__ emb_u, const float* __restrict__ emb_s1,
    const float* __restrict__ emb_s2, const float* __restrict__ emb_s3,
    const unsigned short* __restrict__ sw1, const float* __restrict__ b1,
    const unsigned short* __restrict__ sw21, const float* __restrict__ b21,
    const float* __restrict__ c2,
    const unsigned short* __restrict__ sw3, const float* __restrict__ fb1,
    const float* __restrict__ fw21, const float* __restrict__ fb21,
    const float* __restrict__ fw22, const float* __restrict__ fb22,
    float* __restrict__ logm, float* __restrict__ logv)
{
    __shared__ unsigned short buf[32*H1_S];   // 33280 B, aliased per phase
    unsigned short* xs  = buf;                // [32][XS_S]
    unsigned short* h1s = buf;                // [32][H1_S]
    unsigned short* xcs = buf;                // [32][XC_S]
    float* pmv = (float*)&buf[32*XC_S];       // pm[4][32] | pv[4][32]  (beyond xcs)

    const int tid  = threadIdx.x;
    const int wid  = tid >> 6;
    const int lane = tid & 63;
    const int lo   = lane & 15;
    const int hi   = lane >> 4;
    const int r0   = blockIdx.x * TM;
    const int b    = r0 >> 7;

    // ---- prefetch GEMM1 ks=0 A-fragments (coalesced lane*16B) ----
    short8 afp[8];
    #pragma unroll
    for (int mt=0;mt<8;++mt)
        afp[mt] = *(const short8*)&sw1[((wid*8+mt)*5 + 0)*512 + lane*8];

    // ---- gather x rows (row-major bf16 [32][XS_S]) ----
    {
        int row = tid >> 3, seg = tid & 7;
        int road = roads[r0 + row];
        const float* src = emb_u + (long)map_u[road]*128 + seg*16;
        #pragma unroll
        for (int i=0;i<4;++i) {
            float4 v = *(const float4*)&src[i*4];
            *(uint2*)&xs[row*XS_S + seg*16 + i*4] = pack4bf(v.x, v.y, v.z, v.w);
        }
    }
    for (int idx = tid; idx < 32*32; idx += 256) {
        int row = idx >> 5, k2 = idx & 31;
        int road = roads[r0 + row];
        float v;
        if      (k2 < 16) v = emb_s1[map_s1[road]*16 + k2];
        else if (k2 < 24) v = emb_s2[map_s2[road]*8  + (k2-16)];
        else if (k2 < 28) v = emb_s3[map_s3[road]*4  + (k2-24)];
        else              v = 0.f;
        xs[row*XS_S + 128 + k2] = f2bf(v);
    }
    __syncthreads();

    // ---- GEMM1: h1^T = W1 x X^T   (Nout=512, K=160) ----
    short8 a2p0, a2p1;
    f32x4 acc1[8][2];
    {
        #pragma unroll
        for (int mt=0;mt<8;++mt){ acc1[mt][0]=(f32x4)(0.f); acc1[mt][1]=(f32x4)(0.f); }
        {
            short8 bf0 = *(const short8*)&xs[lo*XS_S + hi*8];
            short8 bf1 = *(const short8*)&xs[(16+lo)*XS_S + hi*8];
            #pragma unroll
            for (int mt=0;mt<8;++mt) {
                acc1[mt][0] = __builtin_amdgcn_mfma_f32_16x16x32_bf16(afp[mt], bf0, acc1[mt][0], 0,0,0);
                acc1[mt][1] = __builtin_amdgcn_mfma_f32_16x16x32_bf16(afp[mt], bf1, acc1[mt][1], 0,0,0);
            }
        }
        #pragma unroll
        for (int ks=1; ks<5; ++ks) {
            const int kb = ks*32 + hi*8;
            short8 bf0 = *(const short8*)&xs[lo*XS_S + kb];
            short8 bf1 = *(const short8*)&xs[(16+lo)*XS_S + kb];
            short8 af[8];
            #pragma unroll
            for (int mt=0;mt<8;++mt)
                af[mt] = *(const short8*)&sw1[((wid*8+mt)*5 + ks)*512 + lane*8];
            #pragma unroll
            for (int mt=0;mt<8;++mt) {
                acc1[mt][0] = __builtin_amdgcn_mfma_f32_16x16x32_bf16(af[mt], bf0, acc1[mt][0], 0,0,0);
                acc1[mt][1] = __builtin_amdgcn_mfma_f32_16x16x32_bf16(af[mt], bf1, acc1[mt][1], 0,0,0);
            }
        }
    }
    __syncthreads();          // all xs reads complete -> safe to overwrite as h1s

    {
        a2p0 = *(const short8*)&sw21[((wid*2+0)*16 + 0)*512 + lane*8];
        a2p1 = *(const short8*)&sw21[((wid*2+1)*16 + 0)*512 + lane*8];
        const int n0 = wid * 128;
        #pragma unroll
        for (int mt=0;mt<8;++mt) {
            const int nb = n0 + mt*16 + hi*4;
            float4 bias = *(const float4*)&b1[nb];
            const float* bp = (const float*)&bias;
            #pragma unroll
            for (int nt=0;nt<2;++nt) {
                const float* a = (const float*)&acc1[mt][nt];
                float y0 = fmaxf(a[0]+bp[0], 0.f), y1 = fmaxf(a[1]+bp[1], 0.f);
                float y2 = fmaxf(a[2]+bp[2], 0.f), y3 = fmaxf(a[3]+bp[3], 0.f);
                *(uint2*)&h1s[(nt*16+lo)*H1_S + nb] = pack4bf(y0,y1,y2,y3);
            }
        }
    }
    __syncthreads();          // h1s ready

    // ---- GEMM2: rho^T = W21 x h1^T  (Nout=128, K=512) ----
    short8 a3p[8];
    f32x4 acc2[2][2];
    {
        acc2[0][0]=(f32x4)(0.f); acc2[0][1]=(f32x4)(0.f);
        acc2[1][0]=(f32x4)(0.f); acc2[1][1]=(f32x4)(0.f);
        {
            short8 bf0 = *(const short8*)&h1s[lo*H1_S + hi*8];
            short8 bf1 = *(const short8*)&h1s[(16+lo)*H1_S + hi*8];
            acc2[0][0] = __builtin_amdgcn_mfma_f32_16x16x32_bf16(a2p0, bf0, acc2[0][0], 0,0,0);
            acc2[0][1] = __builtin_amdgcn_mfma_f32_16x16x32_bf16(a2p0, bf1, acc2[0][1], 0,0,0);
            acc2[1][0] = __builtin_amdgcn_mfma_f32_16x16x32_bf16(a2p1, bf0, acc2[1][0], 0,0,0);
            acc2[1][1] = __builtin_amdgcn_mfma_f32_16x16x32_bf16(a2p1, bf1, acc2[1][1], 0,0,0);
        }
        #pragma unroll 5
        for (int ks=1; ks<16; ++ks) {
            const int kb = ks*32 + hi*8;
            short8 bf0 = *(const short8*)&h1s[lo*H1_S + kb];
            short8 bf1 = *(const short8*)&h1s[(16+lo)*H1_S + kb];
            short8 a0 = *(const short8*)&sw21[((wid*2+0)*16 + ks)*512 + lane*8];
            short8 a1 = *(const short8*)&sw21[((wid*2+1)*16 + ks)*512 + lane*8];
            acc2[0][0] = __builtin_amdgcn_mfma_f32_16x16x32_bf16(a0, bf0, acc2[0][0], 0,0,0);
            acc2[0][1] = __builtin_amdgcn_mfma_f32_16x16x32_bf16(a0, bf1, acc2[0][1], 0,0,0);
            acc2[1][0] = __builtin_amdgcn_mfma_f32_16x16x32_bf16(a1, bf0, acc2[1][0], 0,0,0);
            acc2[1][1] = __builtin_amdgcn_mfma_f32_16x16x32_bf16(a1, bf1, acc2[1][1], 0,0,0);
        }
    }
    __syncthreads();          // all h1s reads complete -> safe to overwrite as xcs

    {
        #pragma unroll
        for (int mt=0;mt<8;++mt)
            a3p[mt] = *(const short8*)&sw3[((wid*8+mt)*8 + 0)*512 + lane*8];
        const int n02 = wid * 32;
        #pragma unroll
        for (int mt=0;mt<2;++mt) {
            const int nb = n02 + mt*16 + hi*4;
            float4 bias = *(const float4*)&b21[nb];
            const float* bp = (const float*)&bias;
            #pragma unroll
            for (int nt=0;nt<2;++nt) {
                const float* a = (const float*)&acc2[mt][nt];
                *(uint2*)&xcs[(nt*16+lo)*XC_S + nb] =
                    pack4bf(a[0]+bp[0], a[1]+bp[1], a[2]+bp[2], a[3]+bp[3]);
            }
        }
        int row = tid >> 3, seg = tid & 7;
        const float* src = c2 + b*128 + seg*16;
        #pragma unroll
        for (int i=0;i<4;++i) {
            float4 v = *(const float4*)&src[i*4];
            *(uint2*)&xcs[row*XC_S + 128 + seg*16 + i*4] = pack4bf(v.x, v.y, v.z, v.w);
        }
    }
    __syncthreads();          // xcs ready

    // ---- GEMM3: h3^T = FW1 x xcat^T (Nout=512, K=256) + fused dual dot ----
    {
        const int n0 = wid * 128;
        f32x4 acc[8][2];
        #pragma unroll
        for (int mt=0;mt<8;++mt){ acc[mt][0]=(f32x4)(0.f); acc[mt][1]=(f32x4)(0.f); }
        {
            short8 bf0 = *(const short8*)&xcs[lo*XC_S + hi*8];
            short8 bf1 = *(const short8*)&xcs[(16+lo)*XC_S + hi*8];
            #pragma unroll
            for (int mt=0;mt<8;++mt) {
                acc[mt][0] = __builtin_amdgcn_mfma_f32_16x16x32_bf16(a3p[mt], bf0, acc[mt][0], 0,0,0);
                acc[mt][1] = __builtin_amdgcn_mfma_f32_16x16x32_bf16(a3p[mt], bf1, acc[mt][1], 0,0,0);
            }
        }
        #pragma unroll 3
        for (int ks=1; ks<8; ++ks) {
            const int kb = ks*32 + hi*8;
            short8 bf0 = *(const short8*)&xcs[lo*XC_S + kb];
            short8 bf1 = *(const short8*)&xcs[(16+lo)*XC_S + kb];
            short8 af[8];
            #pragma unroll
            for (int mt=0;mt<8;++mt)
                af[mt] = *(const short8*)&sw3[((wid*8+mt)*8 + ks)*512 + lane*8];
            #pragma unroll
            for (int mt=0;mt<8;++mt) {
                acc[mt][0] = __builtin_amdgcn_mfma_f32_16x16x32_bf16(af[mt], bf0, acc[mt][0], 0,0,0);
                acc[mt][1] = __builtin_amdgcn_mfma_f32_16x16x32_bf16(af[mt], bf1, acc[mt][1], 0,0,0);
            }
        }
        float sm0=0.f, sm1=0.f, sv0=0.f, sv1=0.f;
        #pragma unroll
        for (int mt=0;mt<8;++mt) {
            const int nb = n0 + mt*16 + hi*4;
            float4 bias = *(const float4*)&fb1[nb];
            float4 wm   = *(const float4*)&fw21[nb];
            float4 wv   = *(const float4*)&fw22[nb];
            const float *bp=(const float*)&bias, *wmp=(const float*)&wm, *wvp=(const float*)&wv;
            const float* a0 = (const float*)&acc[mt][0];
            const float* a1 = (const float*)&acc[mt][1];
            #pragma unroll
            for (int j=0;j<4;++j) {
                float y0 = fmaxf(a0[j]+bp[j], 0.f);
                float y1 = fmaxf(a1[j]+bp[j], 0.f);
                sm0 += y0*wmp[j]; sv0 += y0*wvp[j];
                sm1 += y1*wmp[j]; sv1 += y1*wvp[j];
            }
        }
        sm0 += __shfl_xor(sm0, 16, 64); sm0 += __shfl_xor(sm0, 32, 64);
        sm1 += __shfl_xor(sm1, 16, 64); sm1 += __shfl_xor(sm1, 32, 64);
        sv0 += __shfl_xor(sv0, 16, 64); sv0 += __shfl_xor(sv0, 32, 64);
        sv1 += __shfl_xor(sv1, 16, 64); sv1 += __shfl_xor(sv1, 32, 64);
        if (hi == 0) {
            pmv[wid*32 + lo]        = sm0;
            pmv[wid*32 + 16 + lo]   = sm1;
            pmv[128 + wid*32 + lo]      = sv0;
            pmv[128 + wid*32 + 16 + lo] = sv1;
        }
    }
    __syncthreads();
    if (tid < 32) {
        float sm = pmv[tid]+pmv[32+tid]+pmv[64+tid]+pmv[96+tid];
        float sv = pmv[128+tid]+pmv[160+tid]+pmv[192+tid]+pmv[224+tid];
        logm[r0+tid] = sm + fb21[0];
        logv[r0+tid] = sv + fb22[0];
    }
}

// ================= final per-trajectory reduction =================
__global__ __launch_bounds__(64) void final_kernel(
    const int* __restrict__ roads, const float* __restrict__ ratios,
    const float* __restrict__ lengths,
    const float* __restrict__ logm, const float* __restrict__ logv,
    float* __restrict__ out)
{
    int b = blockIdx.x;
    int lane = threadIdx.x;
    int i0 = b*128 + lane;
    int i1 = i0 + 64;
    float rl0 = lengths[roads[i0]] * ratios[i0];
    float rl1 = lengths[roads[i1]] * ratios[i1];

    float tsum = rl0 + rl1;
    #pragma unroll
    for (int off=32; off; off>>=1) tsum += __shfl_xor(tsum, off, 64);
    float l = tsum;
    float logl = logf(l);

    float lw0 = logf(rl0) - logl;
    float lw1 = logf(rl1) - logl;

    float am0 = logm[i0] + lw0, am1 = logm[i1] + lw1;
    float av0 = logv[i0] + 2.f*lw0, av1 = logv[i1] + 2.f*lw1;

    float mm = fmaxf(am0, am1);
    #pragma unroll
    for (int off=32; off; off>>=1) mm = fmaxf(mm, __shfl_xor(mm, off, 64));
    float se = expf(am0-mm) + expf(am1-mm);
    #pragma unroll
    for (int off=32; off; off>>=1) se += __shfl_xor(se, off, 64);
    float lsem = logf(se) + mm;

    float mv = fmaxf(av0, av1);
    #pragma unroll
    for (int off=32; off; off>>=1) mv = fmaxf(mv, __shfl_xor(mv, off, 64));
    float sev = expf(av0-mv) + expf(av1-mv);
    #pragma unroll
    for (int off=32; off; off>>=1) sev += __shfl_xor(sev, off, 64);
    float lsev = logf(sev) + mv;

    if (lane == 0) {
        out[b]       = logl - lsem;
        out[512 + b] = logl - 3.f*lsem - lsev;
    }
}

extern "C" void kernel_launch(void* const* d_in, const int* in_sizes, int n_in,
                              void* d_out, int out_size, void* d_ws, size_t ws_size,
                              hipStream_t stream) {
    const int*   roads   = (const int*)  d_in[0];
    const float* ratios  = (const float*)d_in[1];
    const float* T       = (const float*)d_in[2];
    const int*   lon_idx = (const int*)  d_in[3];
    const int*   lat_idx = (const int*)  d_in[4];
    const float* lengths = (const float*)d_in[5];
    const int*   map_u   = (const int*)  d_in[6];
    const int*   map_s1  = (const int*)  d_in[7];
    const int*   map_s2  = (const int*)  d_in[8];
    const int*   map_s3  = (const int*)  d_in[9];
    const float* emb_u   = (const float*)d_in[10];
    const float* emb_s1  = (const float*)d_in[11];
    const float* emb_s2  = (const float*)d_in[12];
    const float* emb_s3  = (const float*)d_in[13];
    const float* rho_w1  = (const float*)d_in[14];
    const float* rho_b1  = (const float*)d_in[15];
    const float* rho_w21 = (const float*)d_in[16];
    const float* rho_b21 = (const float*)d_in[17];
    const float* conv1_w = (const float*)d_in[18];
    const float* conv1_b = (const float*)d_in[19];
    const float* bn1_g   = (const float*)d_in[20];
    const float* bn1_b   = (const float*)d_in[21];
    const float* conv2_w = (const float*)d_in[22];
    const float* conv2_b = (const float*)d_in[23];
    const float* bn2_g   = (const float*)d_in[24];
    const float* bn2_b   = (const float*)d_in[25];
    const float* conv3_w = (const float*)d_in[26];
    const float* conv3_b = (const float*)d_in[27];
    const float* bn3_g   = (const float*)d_in[28];
    const float* bn3_b   = (const float*)d_in[29];
    const float* f2_w1   = (const float*)d_in[30];
    const float* f2_b1   = (const float*)d_in[31];
    const float* f2_w2   = (const float*)d_in[32];
    const float* f2_b2   = (const float*)d_in[33];
    const float* f_w1    = (const float*)d_in[34];
    const float* f_b1    = (const float*)d_in[35];
    const float* f_w21   = (const float*)d_in[36];
    const float* f_b21   = (const float*)d_in[37];
    const float* f_w22   = (const float*)d_in[38];
    const float* f_b22   = (const float*)d_in[39];

    float* ws    = (float*)d_ws;
    float* t1    = ws;              // [4624][32]  channels-last
    float* t2    = t1 + 147968;     // [1156][64]  channels-last
    float* t3T   = t2 + 73984;      // [289][128]
    float* c2b   = t3T + 36992;
    float* logm  = c2b + 65536;
    float* logv  = logm + 65536;
    float* w2t   = logv + 65536;    // 32768
    float* w3t   = w2t + 32768;     // 131072
    unsigned short* sw1  = (unsigned short*)(w3t + 131072);  // 81920
    unsigned short* sw21 = sw1 + 81920;                      // 65536
    unsigned short* sw3  = sw21 + 65536;                     // 131072

    combo1_kernel<<<PREP_BLOCKS + CONV1_BLOCKS, 256, 0, stream>>>(
        rho_w1, rho_w21, f_w1, sw1, sw21, sw3,
        conv2_w, conv3_w, w2t, w3t,
        T, conv1_w, conv1_b, bn1_g, bn1_b, t1);
    conv2_kernel<<<(64*34*34*4 + 255)/256, 256, 0, stream>>>(t1, w2t, conv2_b, bn2_g, bn2_b, t2);
    conv3_kernel<<<(128*289*8 + 255)/256, 256, 0, stream>>>(t2, w3t, conv3_b, bn3_g, bn3_b, t3T);
    cmh2c2_kernel<<<512, 256, 0, stream>>>(t3T, lat_idx, lon_idx, f2_w1, f2_b1, f2_w2, f2_b2, c2b);
    mega_kernel<<<NBLK, 256, 0, stream>>>(roads, map_u, map_s1, map_s2, map_s3,
                                          emb_u, emb_s1, emb_s2, emb_s3,
                                          sw1, rho_b1, sw21, rho_b21,
                                          c2b, sw3, f_b1, f_w21, f_b21, f_w22, f_b22,
                                          logm, logv);
    final_kernel<<<512, 64, 0, stream>>>(roads, ratios, lengths, logm, logv, (float*)d_out);
}

// Round 5
// 117.551 us; speedup vs baseline: 8.1768x; 1.0567x over previous
//
#include <hip/hip_runtime.h>
#include <math.h>

#define BB 512
#define SS 128
#define NROWS (BB*SS)      // 65536
#define TMG 64             // rows per mega block
#define NBLKG (NROWS/TMG)  // 1024

__device__ __forceinline__ float leaky01(float x){ return x >= 0.f ? x : 0.1f*x; }

#define BN_INV 0.9999950000374997f
#define SELU_A 1.6732632423543772f
#define SELU_S 1.0507009873554805f

typedef __attribute__((ext_vector_type(8))) short short8;
typedef __attribute__((ext_vector_type(4))) float f32x4;

__device__ __forceinline__ unsigned short f2bf(float f) {
    unsigned int u = __float_as_uint(f);
    u += 0x7fff + ((u >> 16) & 1);          // round-to-nearest-even
    return (unsigned short)(u >> 16);
}
__device__ __forceinline__ uint2 pack4bf(float a, float b, float c, float d) {
    uint2 r;
    r.x = (unsigned int)f2bf(a) | ((unsigned int)f2bf(b) << 16);
    r.y = (unsigned int)f2bf(c) | ((unsigned int)f2bf(d) << 16);
    return r;
}

// h1 tile: [64][512] bf16, unpadded, XOR-swizzled: byte ^= (row&7)<<4.
// 8B writes and 16B reads both stay aligned (only bits>=4 flip).
__device__ __forceinline__ unsigned short* h1p(unsigned short* base, int row, int col) {
    unsigned off = (unsigned)(row*1024 + col*2);
    off ^= (unsigned)((row & 7) << 4);
    return (unsigned short*)((char*)base + off);
}

// ================= combo: weight swizzle-prep + conv1 =================
#define PREP_N (278528 + 32768 + 131072)   // 442368
#define PREP_BLOCKS (PREP_N/256)           // 1728
#define CONV1_BLOCKS 578                   // ceil(147968/256)

__global__ __launch_bounds__(256) void combo1_kernel(
    const float* __restrict__ w1, const float* __restrict__ w21, const float* __restrict__ fw1,
    unsigned short* __restrict__ sw1, unsigned short* __restrict__ sw21, unsigned short* __restrict__ sw3,
    const float* __restrict__ c2w_in, const float* __restrict__ c3w_in,
    float* __restrict__ w2t, float* __restrict__ w3t,
    const float* __restrict__ T, const float* __restrict__ cw,
    const float* __restrict__ cbias, const float* __restrict__ g,
    const float* __restrict__ bb, float* __restrict__ out)   // out: t1 channels-last [pos68][32]
{
    if (blockIdx.x < PREP_BLOCKS) {
        int t = blockIdx.x*256 + threadIdx.x;
        if (t < 81920) {                       // sw1: 32 ntiles x 5 ks   (w1 [156][512], pad->160)
            int j = t & 7; int r = t >> 3; int lane = r & 63; r >>= 6;
            int ks = r % 5; int nt = r / 5;
            int n = nt*16 + (lane & 15);
            int k = ks*32 + (lane >> 4)*8 + j;
            float v = (k < 156) ? w1[k*512 + n] : 0.f;
            sw1[t] = f2bf(v);
        } else if (t < 147456) {               // sw21: 8 ntiles x 16 ks  (w21 [512][128])
            int u = t - 81920;
            int j = u & 7; int r = u >> 3; int lane = r & 63; r >>= 6;
            int ks = r & 15; int nt = r >> 4;
            int d = nt*16 + (lane & 15);
            int k = ks*32 + (lane >> 4)*8 + j;
            sw21[u] = f2bf(w21[k*128 + d]);
        } else if (t < 278528) {               // sw3: 32 ntiles x 8 ks   (fw1 [256][512])
            int u = t - 147456;
            int j = u & 7; int r = u >> 3; int lane = r & 63; r >>= 6;
            int ks = r & 7; int nt = r >> 3;
            int n = nt*16 + (lane & 15);
            int k = ks*32 + (lane >> 4)*8 + j;
            sw3[u] = f2bf(fw1[k*512 + n]);
        } else if (t < 278528 + 32768) {       // w2t[oc][kk][ic]
            int u = t - 278528;
            int oc = u >> 9; int r = u & 511;
            int kk = r >> 5; int ic = r & 31;
            w2t[u] = c2w_in[oc*512 + ic*16 + kk];
        } else {                               // w3t[oc][kk][ic]
            int u = t - (278528 + 32768);
            int oc = u >> 10; int r = u & 1023;
            int kk = r >> 6; int ic = r & 63;
            w3t[u] = c3w_in[oc*1024 + ic*16 + kk];
        }
    } else {
        int t = (blockIdx.x - PREP_BLOCKS)*256 + threadIdx.x;
        if (t >= 32*68*68) return;
        int oc  = t & 31;
        int pos = t >> 5;
        int oy = pos / 68, ox = pos % 68;
        float acc = cbias[oc];
        #pragma unroll
        for (int ky=0; ky<5; ++ky) {
            int iy = oy*2 - 1 + ky;
            if (iy < 0 || iy >= 138) continue;
            #pragma unroll
            for (int kx=0; kx<5; ++kx) {
                int ix = ox*2 - 1 + kx;
                if (ix < 0 || ix >= 138) continue;
                acc += cw[oc*25 + ky*5 + kx] * T[iy*138 + ix];
            }
        }
        acc = acc * (g[oc]*BN_INV) + bb[oc];
        out[pos*32 + oc] = leaky01(acc);
    }
}

// ================= conv2: channels-last, 4 lanes per output (8 ic each) =================
__global__ __launch_bounds__(256) void conv2_kernel(
    const float* __restrict__ in,      // [pos68][32]
    const float* __restrict__ w2t,     // [oc][kk][ic32]
    const float* __restrict__ bias, const float* __restrict__ g,
    const float* __restrict__ bb, float* __restrict__ out)   // [pos34][64]
{
    int gid = blockIdx.x*256 + threadIdx.x;
    if (gid >= 64*34*34*4) return;
    int icg = gid & 3;
    int o   = gid >> 2;
    int oc  = o & 63;
    int pos = o >> 6;
    int oy = pos / 34, ox = pos % 34;
    float acc = 0.f;
    #pragma unroll
    for (int ky=0; ky<4; ++ky) {
        int iy = oy*2 - 1 + ky;
        if (iy < 0 || iy >= 68) continue;
        #pragma unroll
        for (int kx=0; kx<4; ++kx) {
            int ix = ox*2 - 1 + kx;
            if (ix < 0 || ix >= 68) continue;
            const float* ip = &in[(iy*68+ix)*32 + icg*8];
            const float* wp = &w2t[oc*512 + (ky*4+kx)*32 + icg*8];
            float4 i0 = *(const float4*)ip, i1 = *(const float4*)(ip+4);
            float4 w0 = *(const float4*)wp, w1v = *(const float4*)(wp+4);
            acc += i0.x*w0.x + i0.y*w0.y + i0.z*w0.z + i0.w*w0.w
                 + i1.x*w1v.x + i1.y*w1v.y + i1.z*w1v.z + i1.w*w1v.w;
        }
    }
    acc += __shfl_xor(acc, 1, 64);
    acc += __shfl_xor(acc, 2, 64);
    if (icg == 0) {
        acc = (acc + bias[oc]) * (g[oc]*BN_INV) + bb[oc];
        out[pos*64 + oc] = leaky01(acc);
    }
}

// ================= conv3: channels-last, 8 lanes per output, transposed out =================
__global__ __launch_bounds__(256) void conv3_kernel(
    const float* __restrict__ in,      // [pos34][64]
    const float* __restrict__ w3t,     // [oc][kk][ic64]
    const float* __restrict__ bias, const float* __restrict__ g,
    const float* __restrict__ bb, float* __restrict__ outT)  // [pos17][128]
{
    int gid = blockIdx.x*256 + threadIdx.x;
    if (gid >= 128*289*8) return;
    int icg = gid & 7;
    int o   = gid >> 3;
    int oc  = o & 127;
    int pos = o >> 7;
    int oy = pos / 17, ox = pos % 17;
    float acc = 0.f;
    #pragma unroll
    for (int ky=0; ky<4; ++ky) {
        int iy = oy*2 - 1 + ky;
        if (iy < 0 || iy >= 34) continue;
        #pragma unroll
        for (int kx=0; kx<4; ++kx) {
            int ix = ox*2 - 1 + kx;
            if (ix < 0 || ix >= 34) continue;
            const float* ip = &in[(iy*34+ix)*64 + icg*8];
            const float* wp = &w3t[oc*1024 + (ky*4+kx)*64 + icg*8];
            float4 i0 = *(const float4*)ip, i1 = *(const float4*)(ip+4);
            float4 w0 = *(const float4*)wp, w1v = *(const float4*)(wp+4);
            acc += i0.x*w0.x + i0.y*w0.y + i0.z*w0.z + i0.w*w0.w
                 + i1.x*w1v.x + i1.y*w1v.y + i1.z*w1v.z + i1.w*w1v.w;
        }
    }
    acc += __shfl_xor(acc, 1, 64);
    acc += __shfl_xor(acc, 2, 64);
    acc += __shfl_xor(acc, 4, 64);
    if (icg == 0) {
        acc = (acc + bias[oc]) * (g[oc]*BN_INV) + bb[oc];
        outT[pos*128 + oc] = leaky01(acc);
    }
}

// ================= fused cmean -> h2(selu) -> c2, one block per b =================
__global__ __launch_bounds__(256) void cmh2c2_kernel(
    const float* __restrict__ t3T, const int* __restrict__ lat, const int* __restrict__ lon,
    const float* __restrict__ w1, const float* __restrict__ b1,
    const float* __restrict__ w2, const float* __restrict__ b2,
    float* __restrict__ c2b)
{
    __shared__ int   ps[64];
    __shared__ float part[256];
    __shared__ float cms[128];
    __shared__ float h2s[256];
    const int b = blockIdx.x;
    const int tid = threadIdx.x;
    if (tid < 64) ps[tid] = lat[b*64+tid]*17 + lon[b*64+tid];
    __syncthreads();
    {
        int d = tid & 127, half = tid >> 7;
        float s = 0.f;
        #pragma unroll 8
        for (int k=0; k<32; ++k) s += t3T[ps[half*32+k]*128 + d];
        part[tid] = s;
    }
    __syncthreads();
    if (tid < 128) cms[tid] = (part[tid] + part[tid+128]) * (1.f/64.f);
    __syncthreads();
    {
        float acc = b1[tid];
        #pragma unroll 8
        for (int k=0; k<128; ++k) acc += cms[k] * w1[k*256 + tid];
        h2s[tid] = acc > 0.f ? SELU_S*acc : SELU_S*SELU_A*(expf(acc)-1.f);
    }
    __syncthreads();
    {
        int d = tid & 127, half = tid >> 7;
        float acc = 0.f;
        #pragma unroll 8
        for (int k=0; k<128; ++k) acc += h2s[half*128 + k] * w2[(half*128+k)*128 + d];
        part[tid] = acc;
    }
    __syncthreads();
    if (tid < 128) c2b[b*128 + tid] = part[tid] + part[tid+128] + b2[tid];
}

// ================= fused per-row mega kernel: 64 rows/block, 8 waves =================
// Single 64KB LDS buffer aliased: xs[64][168] -> h1(swizzled [64][512]) -> xcs[64][264] -> pm/pv
#define XS_S 168
#define XC_S 264

__global__ __launch_bounds__(512, 4) void mega_kernel(
    const int* __restrict__ roads,
    const int* __restrict__ map_u, const int* __restrict__ map_s1,
    const int* __restrict__ map_s2, const int* __restrict__ map_s3,
    const float* __restrict__ emb_u, const float* __restrict__ emb_s1,
    const float* __restrict__ emb_s2, const float* __restrict__ emb_s3,
    const unsigned short* __restrict__ sw1, const float* __restrict__ b1,
    const unsigned short* __restrict__ sw21, const float* __restrict__ b21,
    const float* __restrict__ c2,
    const unsigned short* __restrict__ sw3, const float* __restrict__ fb1,
    const float* __restrict__ fw21, const float* __restrict__ fb21,
    const float* __restrict__ fw22, const float* __restrict__ fb22,
    float* __restrict__ logm, float* __restrict__ logv)
{
    __shared__ unsigned short buf[32768];     // 65536 B, aliased per phase
    unsigned short* xs  = buf;                // [64][XS_S]
    unsigned short* xcs = buf;                // [64][XC_S]
    float* pmv = (float*)buf;                 // pm[8][64] | pv[8][64] after GEMM3

    const int tid  = threadIdx.x;
    const int wid  = tid >> 6;                // 0..7
    const int lane = tid & 63;
    const int lo   = lane & 15;
    const int hi   = lane >> 4;
    const int r0   = blockIdx.x * TMG;
    const int b    = r0 >> 7;                 // all 64 rows share one b

    // ---- prefetch GEMM1 ks=0 A-fragments ----
    short8 afp[4];
    #pragma unroll
    for (int mt=0;mt<4;++mt)
        afp[mt] = *(const short8*)&sw1[((wid*4+mt)*5 + 0)*512 + lane*8];

    // ---- gather x rows (row-major bf16 [64][XS_S]) ----
    {
        int row = tid >> 3, seg = tid & 7;
        int road = roads[r0 + row];
        const float* src = emb_u + (long)map_u[road]*128 + seg*16;
        #pragma unroll
        for (int i=0;i<4;++i) {
            float4 v = *(const float4*)&src[i*4];
            *(uint2*)&xs[row*XS_S + seg*16 + i*4] = pack4bf(v.x, v.y, v.z, v.w);
        }
    }
    for (int idx = tid; idx < 64*32; idx += 512) {
        int row = idx >> 5, k2 = idx & 31;
        int road = roads[r0 + row];
        float v;
        if      (k2 < 16) v = emb_s1[map_s1[road]*16 + k2];
        else if (k2 < 24) v = emb_s2[map_s2[road]*8  + (k2-16)];
        else if (k2 < 28) v = emb_s3[map_s3[road]*4  + (k2-24)];
        else              v = 0.f;
        xs[row*XS_S + 128 + k2] = f2bf(v);
    }
    __syncthreads();

    // ---- GEMM1: h1^T = W1 x X^T   (Nout=512, K=160); wave owns 64 N-cols ----
    short8 a2p;
    f32x4 acc1[4][4];
    {
        #pragma unroll
        for (int mt=0;mt<4;++mt)
            #pragma unroll
            for (int rg=0;rg<4;++rg) acc1[mt][rg]=(f32x4)(0.f);
        #pragma unroll
        for (int ks=0; ks<5; ++ks) {
            const int kb = ks*32 + hi*8;
            short8 bf[4];
            #pragma unroll
            for (int rg=0;rg<4;++rg)
                bf[rg] = *(const short8*)&xs[(rg*16+lo)*XS_S + kb];
            short8 af[4];
            if (ks == 0) {
                #pragma unroll
                for (int mt=0;mt<4;++mt) af[mt] = afp[mt];
            } else {
                #pragma unroll
                for (int mt=0;mt<4;++mt)
                    af[mt] = *(const short8*)&sw1[((wid*4+mt)*5 + ks)*512 + lane*8];
            }
            #pragma unroll
            for (int mt=0;mt<4;++mt)
                #pragma unroll
                for (int rg=0;rg<4;++rg)
                    acc1[mt][rg] = __builtin_amdgcn_mfma_f32_16x16x32_bf16(af[mt], bf[rg], acc1[mt][rg], 0,0,0);
        }
    }
    __syncthreads();          // xs reads complete -> reuse buf as h1

    {
        a2p = *(const short8*)&sw21[(wid*16 + 0)*512 + lane*8];
        const int n0 = wid * 64;
        #pragma unroll
        for (int mt=0;mt<4;++mt) {
            const int nb = n0 + mt*16 + hi*4;
            float4 bias = *(const float4*)&b1[nb];
            const float* bp = (const float*)&bias;
            #pragma unroll
            for (int rg=0;rg<4;++rg) {
                const float* a = (const float*)&acc1[mt][rg];
                float y0 = fmaxf(a[0]+bp[0], 0.f), y1 = fmaxf(a[1]+bp[1], 0.f);
                float y2 = fmaxf(a[2]+bp[2], 0.f), y3 = fmaxf(a[3]+bp[3], 0.f);
                *(uint2*)h1p(buf, rg*16+lo, nb) = pack4bf(y0,y1,y2,y3);
            }
        }
    }
    __syncthreads();          // h1 ready

    // ---- GEMM2: rho^T = W21 x h1^T  (Nout=128, K=512); wave owns 16 N-cols ----
    short8 a3p[4];
    f32x4 acc2[4];
    {
        #pragma unroll
        for (int rg=0;rg<4;++rg) acc2[rg]=(f32x4)(0.f);
        #pragma unroll 4
        for (int ks=0; ks<16; ++ks) {
            const int kb = ks*32 + hi*8;
            short8 bf[4];
            #pragma unroll
            for (int rg=0;rg<4;++rg)
                bf[rg] = *(const short8*)h1p(buf, rg*16+lo, kb);
            short8 a = (ks == 0) ? a2p
                     : *(const short8*)&sw21[(wid*16 + ks)*512 + lane*8];
            #pragma unroll
            for (int rg=0;rg<4;++rg)
                acc2[rg] = __builtin_amdgcn_mfma_f32_16x16x32_bf16(a, bf[rg], acc2[rg], 0,0,0);
        }
    }
    __syncthreads();          // h1 reads complete -> reuse buf as xcs

    {
        #pragma unroll
        for (int mt=0;mt<4;++mt)
            a3p[mt] = *(const short8*)&sw3[((wid*4+mt)*8 + 0)*512 + lane*8];
        const int nb = wid*16 + hi*4;
        float4 bias = *(const float4*)&b21[nb];
        const float* bp = (const float*)&bias;
        #pragma unroll
        for (int rg=0;rg<4;++rg) {
            const float* a = (const float*)&acc2[rg];
            *(uint2*)&xcs[(rg*16+lo)*XC_S + nb] =
                pack4bf(a[0]+bp[0], a[1]+bp[1], a[2]+bp[2], a[3]+bp[3]);
        }
        int row = tid >> 3, seg = tid & 7;
        const float* src = c2 + b*128 + seg*16;
        #pragma unroll
        for (int i=0;i<4;++i) {
            float4 v = *(const float4*)&src[i*4];
            *(uint2*)&xcs[row*XC_S + 128 + seg*16 + i*4] = pack4bf(v.x, v.y, v.z, v.w);
        }
    }
    __syncthreads();          // xcs ready

    // ---- GEMM3: h3^T = FW1 x xcat^T (Nout=512, K=256) + fused dual dot ----
    {
        const int n0 = wid * 64;
        f32x4 acc[4][4];
        #pragma unroll
        for (int mt=0;mt<4;++mt)
            #pragma unroll
            for (int rg=0;rg<4;++rg) acc[mt][rg]=(f32x4)(0.f);
        #pragma unroll 2
        for (int ks=0; ks<8; ++ks) {
            const int kb = ks*32 + hi*8;
            short8 bf[4];
            #pragma unroll
            for (int rg=0;rg<4;++rg)
                bf[rg] = *(const short8*)&xcs[(rg*16+lo)*XC_S + kb];
            short8 af[4];
            if (ks == 0) {
                #pragma unroll
                for (int mt=0;mt<4;++mt) af[mt] = a3p[mt];
            } else {
                #pragma unroll
                for (int mt=0;mt<4;++mt)
                    af[mt] = *(const short8*)&sw3[((wid*4+mt)*8 + ks)*512 + lane*8];
            }
            #pragma unroll
            for (int mt=0;mt<4;++mt)
                #pragma unroll
                for (int rg=0;rg<4;++rg)
                    acc[mt][rg] = __builtin_amdgcn_mfma_f32_16x16x32_bf16(af[mt], bf[rg], acc[mt][rg], 0,0,0);
        }
        float sm[4] = {0.f,0.f,0.f,0.f};
        float sv[4] = {0.f,0.f,0.f,0.f};
        #pragma unroll
        for (int mt=0;mt<4;++mt) {
            const int nb = n0 + mt*16 + hi*4;
            float4 bias = *(const float4*)&fb1[nb];
            float4 wm   = *(const float4*)&fw21[nb];
            float4 wv   = *(const float4*)&fw22[nb];
            const float *bp=(const float*)&bias, *wmp=(const float*)&wm, *wvp=(const float*)&wv;
            #pragma unroll
            for (int rg=0;rg<4;++rg) {
                const float* a = (const float*)&acc[mt][rg];
                #pragma unroll
                for (int j=0;j<4;++j) {
                    float y = fmaxf(a[j]+bp[j], 0.f);
                    sm[rg] += y*wmp[j];
                    sv[rg] += y*wvp[j];
                }
            }
        }
        #pragma unroll
        for (int rg=0;rg<4;++rg) {
            sm[rg] += __shfl_xor(sm[rg], 16, 64); sm[rg] += __shfl_xor(sm[rg], 32, 64);
            sv[rg] += __shfl_xor(sv[rg], 16, 64); sv[rg] += __shfl_xor(sv[rg], 32, 64);
        }
        __syncthreads();      // xcs reads complete -> reuse buf as pm/pv
        if (hi == 0) {
            #pragma unroll
            for (int rg=0;rg<4;++rg) {
                pmv[wid*64 + rg*16 + lo]       = sm[rg];
                pmv[512 + wid*64 + rg*16 + lo] = sv[rg];
            }
        }
    }
    __syncthreads();
    if (tid < 64) {
        float sm = 0.f, sv = 0.f;
        #pragma unroll
        for (int w=0; w<8; ++w) {
            sm += pmv[w*64 + tid];
            sv += pmv[512 + w*64 + tid];
        }
        logm[r0+tid] = sm + fb21[0];
        logv[r0+tid] = sv + fb22[0];
    }
}

// ================= final per-trajectory reduction =================
__global__ __launch_bounds__(64) void final_kernel(
    const int* __restrict__ roads, const float* __restrict__ ratios,
    const float* __restrict__ lengths,
    const float* __restrict__ logm, const float* __restrict__ logv,
    float* __restrict__ out)
{
    int b = blockIdx.x;
    int lane = threadIdx.x;
    int i0 = b*128 + lane;
    int i1 = i0 + 64;
    float rl0 = lengths[roads[i0]] * ratios[i0];
    float rl1 = lengths[roads[i1]] * ratios[i1];

    float tsum = rl0 + rl1;
    #pragma unroll
    for (int off=32; off; off>>=1) tsum += __shfl_xor(tsum, off, 64);
    float l = tsum;
    float logl = logf(l);

    float lw0 = logf(rl0) - logl;
    float lw1 = logf(rl1) - logl;

    float am0 = logm[i0] + lw0, am1 = logm[i1] + lw1;
    float av0 = logv[i0] + 2.f*lw0, av1 = logv[i1] + 2.f*lw1;

    float mm = fmaxf(am0, am1);
    #pragma unroll
    for (int off=32; off; off>>=1) mm = fmaxf(mm, __shfl_xor(mm, off, 64));
    float se = expf(am0-mm) + expf(am1-mm);
    #pragma unroll
    for (int off=32; off; off>>=1) se += __shfl_xor(se, off, 64);
    float lsem = logf(se) + mm;

    float mv = fmaxf(av0, av1);
    #pragma unroll
    for (int off=32; off; off>>=1) mv = fmaxf(mv, __shfl_xor(mv, off, 64));
    float sev = expf(av0-mv) + expf(av1-mv);
    #pragma unroll
    for (int off=32; off; off>>=1) sev += __shfl_xor(sev, off, 64);
    float lsev = logf(sev) + mv;

    if (lane == 0) {
        out[b]       = logl - lsem;
        out[512 + b] = logl - 3.f*lsem - lsev;
    }
}

extern "C" void kernel_launch(void* const* d_in, const int* in_sizes, int n_in,
                              void* d_out, int out_size, void* d_ws, size_t ws_size,
                              hipStream_t stream) {
    const int*   roads   = (const int*)  d_in[0];
    const float* ratios  = (const float*)d_in[1];
    const float* T       = (const float*)d_in[2];
    const int*   lon_idx = (const int*)  d_in[3];
    const int*   lat_idx = (const int*)  d_in[4];
    const float* lengths = (const float*)d_in[5];
    const int*   map_u   = (const int*)  d_in[6];
    const int*   map_s1  = (const int*)  d_in[7];
    const int*   map_s2  = (const int*)  d_in[8];
    const int*   map_s3  = (const int*)  d_in[9];
    const float* emb_u   = (const float*)d_in[10];
    const float* emb_s1  = (const float*)d_in[11];
    const float* emb_s2  = (const float*)d_in[12];
    const float* emb_s3  = (const float*)d_in[13];
    const float* rho_w1  = (const float*)d_in[14];
    const float* rho_b1  = (const float*)d_in[15];
    const float* rho_w21 = (const float*)d_in[16];
    const float* rho_b21 = (const float*)d_in[17];
    const float* conv1_w = (const float*)d_in[18];
    const float* conv1_b = (const float*)d_in[19];
    const float* bn1_g   = (const float*)d_in[20];
    const float* bn1_b   = (const float*)d_in[21];
    const float* conv2_w = (const float*)d_in[22];
    const float* conv2_b = (const float*)d_in[23];
    const float* bn2_g   = (const float*)d_in[24];
    const float* bn2_b   = (const float*)d_in[25];
    const float* conv3_w = (const float*)d_in[26];
    const float* conv3_b = (const float*)d_in[27];
    const float* bn3_g   = (const float*)d_in[28];
    const float* bn3_b   = (const float*)d_in[29];
    const float* f2_w1   = (const float*)d_in[30];
    const float* f2_b1   = (const float*)d_in[31];
    const float* f2_w2   = (const float*)d_in[32];
    const float* f2_b2   = (const float*)d_in[33];
    const float* f_w1    = (const float*)d_in[34];
    const float* f_b1    = (const float*)d_in[35];
    const float* f_w21   = (const float*)d_in[36];
    const float* f_b21   = (const float*)d_in[37];
    const float* f_w22   = (const float*)d_in[38];
    const float* f_b22   = (const float*)d_in[39];

    float* ws    = (float*)d_ws;
    float* t1    = ws;              // [4624][32]  channels-last
    float* t2    = t1 + 147968;     // [1156][64]  channels-last
    float* t3T   = t2 + 73984;      // [289][128]
    float* c2b   = t3T + 36992;
    float* logm  = c2b + 65536;
    float* logv  = logm + 65536;
    float* w2t   = logv + 65536;    // 32768
    float* w3t   = w2t + 32768;     // 131072
    unsigned short* sw1  = (unsigned short*)(w3t + 131072);  // 81920
    unsigned short* sw21 = sw1 + 81920;                      // 65536
    unsigned short* sw3  = sw21 + 65536;                     // 131072

    combo1_kernel<<<PREP_BLOCKS + CONV1_BLOCKS, 256, 0, stream>>>(
        rho_w1, rho_w21, f_w1, sw1, sw21, sw3,
        conv2_w, conv3_w, w2t, w3t,
        T, conv1_w, conv1_b, bn1_g, bn1_b, t1);
    conv2_kernel<<<(64*34*34*4 + 255)/256, 256, 0, stream>>>(t1, w2t, conv2_b, bn2_g, bn2_b, t2);
    conv3_kernel<<<(128*289*8 + 255)/256, 256, 0, stream>>>(t2, w3t, conv3_b, bn3_g, bn3_b, t3T);
    cmh2c2_kernel<<<512, 256, 0, stream>>>(t3T, lat_idx, lon_idx, f2_w1, f2_b1, f2_w2, f2_b2, c2b);
    mega_kernel<<<NBLKG, 512, 0, stream>>>(roads, map_u, map_s1, map_s2, map_s3,
                                           emb_u, emb_s1, emb_s2, emb_s3,
                                           sw1, rho_b1, sw21, rho_b21,
                                           c2b, sw3, f_b1, f_w21, f_b21, f_w22, f_b22,
                                           logm, logv);
    final_kernel<<<512, 64, 0, stream>>>(roads, ratios, lengths, logm, logv, (float*)d_out);
}

// Round 6
// 117.173 us; speedup vs baseline: 8.2032x; 1.0032x over previous
//
#include <hip/hip_runtime.h>
#include <math.h>

#define BB 512
#define SS 128
#define NROWS (BB*SS)      // 65536
#define TMG 128            // rows per mega block = one trajectory
#define NBLKG (NROWS/TMG)  // 512

__device__ __forceinline__ float leaky01(float x){ return x >= 0.f ? x : 0.1f*x; }

#define BN_INV 0.9999950000374997f
#define SELU_A 1.6732632423543772f
#define SELU_S 1.0507009873554805f

typedef __attribute__((ext_vector_type(8))) short short8;
typedef __attribute__((ext_vector_type(4))) float f32x4;

__device__ __forceinline__ unsigned short f2bf(float f) {
    unsigned int u = __float_as_uint(f);
    u += 0x7fff + ((u >> 16) & 1);          // round-to-nearest-even
    return (unsigned short)(u >> 16);
}
__device__ __forceinline__ uint2 pack4bf(float a, float b, float c, float d) {
    uint2 r;
    r.x = (unsigned int)f2bf(a) | ((unsigned int)f2bf(b) << 16);
    r.y = (unsigned int)f2bf(c) | ((unsigned int)f2bf(d) << 16);
    return r;
}

// LDS tiles, all row strides multiple of 128B + XOR swizzle (row&7)<<4 -> <=2-way conflicts.
__device__ __forceinline__ unsigned short* xsp(unsigned short* base, int row, int col) {
    unsigned off = (unsigned)(row*384 + col*2);   // [128][192]
    off ^= (unsigned)((row & 7) << 4);
    return (unsigned short*)((char*)base + off);
}
__device__ __forceinline__ unsigned short* h1p(unsigned short* base, int row, int col) {
    unsigned off = (unsigned)(row*1024 + col*2);  // [128][512]
    off ^= (unsigned)((row & 7) << 4);
    return (unsigned short*)((char*)base + off);
}
__device__ __forceinline__ unsigned short* xcp(unsigned short* base, int row, int col) {
    unsigned off = (unsigned)(row*512 + col*2);   // [128][256]
    off ^= (unsigned)((row & 7) << 4);
    return (unsigned short*)((char*)base + off);
}

// ================= combo: weight swizzle-prep + conv1 =================
#define PREP_N (278528 + 32768 + 131072)   // 442368
#define PREP_BLOCKS (PREP_N/256)           // 1728
#define CONV1_BLOCKS 578                   // ceil(147968/256)

__global__ __launch_bounds__(256) void combo1_kernel(
    const float* __restrict__ w1, const float* __restrict__ w21, const float* __restrict__ fw1,
    unsigned short* __restrict__ sw1, unsigned short* __restrict__ sw21, unsigned short* __restrict__ sw3,
    const float* __restrict__ c2w_in, const float* __restrict__ c3w_in,
    float* __restrict__ w2t, float* __restrict__ w3t,
    const float* __restrict__ T, const float* __restrict__ cw,
    const float* __restrict__ cbias, const float* __restrict__ g,
    const float* __restrict__ bb, float* __restrict__ out)   // out: t1 channels-last [pos68][32]
{
    if (blockIdx.x < PREP_BLOCKS) {
        int t = blockIdx.x*256 + threadIdx.x;
        if (t < 81920) {                       // sw1: 32 ntiles x 5 ks   (w1 [156][512], pad->160)
            int j = t & 7; int r = t >> 3; int lane = r & 63; r >>= 6;
            int ks = r % 5; int nt = r / 5;
            int n = nt*16 + (lane & 15);
            int k = ks*32 + (lane >> 4)*8 + j;
            float v = (k < 156) ? w1[k*512 + n] : 0.f;
            sw1[t] = f2bf(v);
        } else if (t < 147456) {               // sw21: 8 ntiles x 16 ks  (w21 [512][128])
            int u = t - 81920;
            int j = u & 7; int r = u >> 3; int lane = r & 63; r >>= 6;
            int ks = r & 15; int nt = r >> 4;
            int d = nt*16 + (lane & 15);
            int k = ks*32 + (lane >> 4)*8 + j;
            sw21[u] = f2bf(w21[k*128 + d]);
        } else if (t < 278528) {               // sw3: 32 ntiles x 8 ks   (fw1 [256][512])
            int u = t - 147456;
            int j = u & 7; int r = u >> 3; int lane = r & 63; r >>= 6;
            int ks = r & 7; int nt = r >> 3;
            int n = nt*16 + (lane & 15);
            int k = ks*32 + (lane >> 4)*8 + j;
            sw3[u] = f2bf(fw1[k*512 + n]);
        } else if (t < 278528 + 32768) {       // w2t[oc][kk][ic]
            int u = t - 278528;
            int oc = u >> 9; int r = u & 511;
            int kk = r >> 5; int ic = r & 31;
            w2t[u] = c2w_in[oc*512 + ic*16 + kk];
        } else {                               // w3t[oc][kk][ic]
            int u = t - (278528 + 32768);
            int oc = u >> 10; int r = u & 1023;
            int kk = r >> 6; int ic = r & 63;
            w3t[u] = c3w_in[oc*1024 + ic*16 + kk];
        }
    } else {
        int t = (blockIdx.x - PREP_BLOCKS)*256 + threadIdx.x;
        if (t >= 32*68*68) return;
        int oc  = t & 31;
        int pos = t >> 5;
        int oy = pos / 68, ox = pos % 68;
        float acc = cbias[oc];
        #pragma unroll
        for (int ky=0; ky<5; ++ky) {
            int iy = oy*2 - 1 + ky;
            if (iy < 0 || iy >= 138) continue;
            #pragma unroll
            for (int kx=0; kx<5; ++kx) {
                int ix = ox*2 - 1 + kx;
                if (ix < 0 || ix >= 138) continue;
                acc += cw[oc*25 + ky*5 + kx] * T[iy*138 + ix];
            }
        }
        acc = acc * (g[oc]*BN_INV) + bb[oc];
        out[pos*32 + oc] = leaky01(acc);
    }
}

// ================= conv2: channels-last, 4 lanes per output (8 ic each) =================
__global__ __launch_bounds__(256) void conv2_kernel(
    const float* __restrict__ in,      // [pos68][32]
    const float* __restrict__ w2t,     // [oc][kk][ic32]
    const float* __restrict__ bias, const float* __restrict__ g,
    const float* __restrict__ bb, float* __restrict__ out)   // [pos34][64]
{
    int gid = blockIdx.x*256 + threadIdx.x;
    if (gid >= 64*34*34*4) return;
    int icg = gid & 3;
    int o   = gid >> 2;
    int oc  = o & 63;
    int pos = o >> 6;
    int oy = pos / 34, ox = pos % 34;
    float acc = 0.f;
    #pragma unroll
    for (int ky=0; ky<4; ++ky) {
        int iy = oy*2 - 1 + ky;
        if (iy < 0 || iy >= 68) continue;
        #pragma unroll
        for (int kx=0; kx<4; ++kx) {
            int ix = ox*2 - 1 + kx;
            if (ix < 0 || ix >= 68) continue;
            const float* ip = &in[(iy*68+ix)*32 + icg*8];
            const float* wp = &w2t[oc*512 + (ky*4+kx)*32 + icg*8];
            float4 i0 = *(const float4*)ip, i1 = *(const float4*)(ip+4);
            float4 w0 = *(const float4*)wp, w1v = *(const float4*)(wp+4);
            acc += i0.x*w0.x + i0.y*w0.y + i0.z*w0.z + i0.w*w0.w
                 + i1.x*w1v.x + i1.y*w1v.y + i1.z*w1v.z + i1.w*w1v.w;
        }
    }
    acc += __shfl_xor(acc, 1, 64);
    acc += __shfl_xor(acc, 2, 64);
    if (icg == 0) {
        acc = (acc + bias[oc]) * (g[oc]*BN_INV) + bb[oc];
        out[pos*64 + oc] = leaky01(acc);
    }
}

// ================= conv3: channels-last, 8 lanes per output, transposed out =================
__global__ __launch_bounds__(256) void conv3_kernel(
    const float* __restrict__ in,      // [pos34][64]
    const float* __restrict__ w3t,     // [oc][kk][ic64]
    const float* __restrict__ bias, const float* __restrict__ g,
    const float* __restrict__ bb, float* __restrict__ outT)  // [pos17][128]
{
    int gid = blockIdx.x*256 + threadIdx.x;
    if (gid >= 128*289*8) return;
    int icg = gid & 7;
    int o   = gid >> 3;
    int oc  = o & 127;
    int pos = o >> 7;
    int oy = pos / 17, ox = pos % 17;
    float acc = 0.f;
    #pragma unroll
    for (int ky=0; ky<4; ++ky) {
        int iy = oy*2 - 1 + ky;
        if (iy < 0 || iy >= 34) continue;
        #pragma unroll
        for (int kx=0; kx<4; ++kx) {
            int ix = ox*2 - 1 + kx;
            if (ix < 0 || ix >= 34) continue;
            const float* ip = &in[(iy*34+ix)*64 + icg*8];
            const float* wp = &w3t[oc*1024 + (ky*4+kx)*64 + icg*8];
            float4 i0 = *(const float4*)ip, i1 = *(const float4*)(ip+4);
            float4 w0 = *(const float4*)wp, w1v = *(const float4*)(wp+4);
            acc += i0.x*w0.x + i0.y*w0.y + i0.z*w0.z + i0.w*w0.w
                 + i1.x*w1v.x + i1.y*w1v.y + i1.z*w1v.z + i1.w*w1v.w;
        }
    }
    acc += __shfl_xor(acc, 1, 64);
    acc += __shfl_xor(acc, 2, 64);
    acc += __shfl_xor(acc, 4, 64);
    if (icg == 0) {
        acc = (acc + bias[oc]) * (g[oc]*BN_INV) + bb[oc];
        outT[pos*128 + oc] = leaky01(acc);
    }
}

// ================= fused cmean -> h2(selu) -> c2, one block per b =================
__global__ __launch_bounds__(256) void cmh2c2_kernel(
    const float* __restrict__ t3T, const int* __restrict__ lat, const int* __restrict__ lon,
    const float* __restrict__ w1, const float* __restrict__ b1,
    const float* __restrict__ w2, const float* __restrict__ b2,
    float* __restrict__ c2b)
{
    __shared__ int   ps[64];
    __shared__ float part[256];
    __shared__ float cms[128];
    __shared__ float h2s[256];
    const int b = blockIdx.x;
    const int tid = threadIdx.x;
    if (tid < 64) ps[tid] = lat[b*64+tid]*17 + lon[b*64+tid];
    __syncthreads();
    {
        int d = tid & 127, half = tid >> 7;
        float s = 0.f;
        #pragma unroll 8
        for (int k=0; k<32; ++k) s += t3T[ps[half*32+k]*128 + d];
        part[tid] = s;
    }
    __syncthreads();
    if (tid < 128) cms[tid] = (part[tid] + part[tid+128]) * (1.f/64.f);
    __syncthreads();
    {
        float acc = b1[tid];
        #pragma unroll 8
        for (int k=0; k<128; ++k) acc += cms[k] * w1[k*256 + tid];
        h2s[tid] = acc > 0.f ? SELU_S*acc : SELU_S*SELU_A*(expf(acc)-1.f);
    }
    __syncthreads();
    {
        int d = tid & 127, half = tid >> 7;
        float acc = 0.f;
        #pragma unroll 8
        for (int k=0; k<128; ++k) acc += h2s[half*128 + k] * w2[(half*128+k)*128 + d];
        part[tid] = acc;
    }
    __syncthreads();
    if (tid < 128) c2b[b*128 + tid] = part[tid] + part[tid+128] + b2[tid];
}

// ================= mega: 128 rows (one trajectory) per block, 16 waves =================
// 128KB LDS buf aliased: xs[128][192] -> h1[128][512] -> xcs[128][256] -> pmv + final scratch
__global__ __launch_bounds__(1024, 4) void mega_kernel(
    const int* __restrict__ roads, const float* __restrict__ ratios,
    const float* __restrict__ lengths,
    const int* __restrict__ map_u, const int* __restrict__ map_s1,
    const int* __restrict__ map_s2, const int* __restrict__ map_s3,
    const float* __restrict__ emb_u, const float* __restrict__ emb_s1,
    const float* __restrict__ emb_s2, const float* __restrict__ emb_s3,
    const unsigned short* __restrict__ sw1, const float* __restrict__ b1,
    const unsigned short* __restrict__ sw21, const float* __restrict__ b21,
    const float* __restrict__ c2,
    const unsigned short* __restrict__ sw3, const float* __restrict__ fb1,
    const float* __restrict__ fw21, const float* __restrict__ fb21,
    const float* __restrict__ fw22, const float* __restrict__ fb22,
    float* __restrict__ out)
{
    __shared__ unsigned short buf[65536];     // 131072 B
    float* pmv = (float*)buf;                 // pm[16][128] | pv[16][128]  (16 KB)
    float* fin = (float*)buf + 4096;          // final-phase scratch (beyond pmv)

    const int tid  = threadIdx.x;
    const int wid  = tid >> 6;                // 0..15
    const int lane = tid & 63;
    const int lo   = lane & 15;
    const int hi   = lane >> 4;
    const int b    = blockIdx.x;
    const int r0   = b * TMG;

    // ---- prefetch GEMM1 ks=0 A-fragments ----
    short8 afp[2];
    #pragma unroll
    for (int mt=0;mt<2;++mt)
        afp[mt] = *(const short8*)&sw1[((wid*2+mt)*5 + 0)*512 + lane*8];

    // ---- gather x rows into xs [128][192] (swizzled) ----
    {
        int row = tid >> 3, seg = tid & 7;
        int road = roads[r0 + row];
        const float* src = emb_u + (long)map_u[road]*128 + seg*16;
        #pragma unroll
        for (int i=0;i<4;++i) {
            float4 v = *(const float4*)&src[i*4];
            *(uint2*)xsp(buf, row, seg*16 + i*4) = pack4bf(v.x, v.y, v.z, v.w);
        }
    }
    for (int idx = tid; idx < 128*32; idx += 1024) {
        int row = idx >> 5, k2 = idx & 31;
        int road = roads[r0 + row];
        float v;
        if      (k2 < 16) v = emb_s1[map_s1[road]*16 + k2];
        else if (k2 < 24) v = emb_s2[map_s2[road]*8  + (k2-16)];
        else if (k2 < 28) v = emb_s3[map_s3[road]*4  + (k2-24)];
        else              v = 0.f;
        *xsp(buf, row, 128 + k2) = f2bf(v);
    }
    __syncthreads();

    // ---- GEMM1: h1^T = W1 x X^T  (Nout=512, K=160); wave owns 32 N-cols, all 128 rows ----
    short8 a2p;
    f32x4 acc1[2][8];
    {
        #pragma unroll
        for (int mt=0;mt<2;++mt)
            #pragma unroll
            for (int rg=0;rg<8;++rg) acc1[mt][rg]=(f32x4)(0.f);
        #pragma unroll
        for (int ks=0; ks<5; ++ks) {
            const int kb = ks*32 + hi*8;
            short8 af[2];
            if (ks == 0) { af[0]=afp[0]; af[1]=afp[1]; }
            else {
                #pragma unroll
                for (int mt=0;mt<2;++mt)
                    af[mt] = *(const short8*)&sw1[((wid*2+mt)*5 + ks)*512 + lane*8];
            }
            #pragma unroll
            for (int rg=0;rg<8;++rg) {
                short8 bf = *(const short8*)xsp(buf, rg*16+lo, kb);
                acc1[0][rg] = __builtin_amdgcn_mfma_f32_16x16x32_bf16(af[0], bf, acc1[0][rg], 0,0,0);
                acc1[1][rg] = __builtin_amdgcn_mfma_f32_16x16x32_bf16(af[1], bf, acc1[1][rg], 0,0,0);
            }
        }
    }
    __syncthreads();          // xs reads complete -> reuse buf as h1

    {
        a2p = *(const short8*)&sw21[((wid>>1)*16 + 0)*512 + lane*8];
        const int n0 = wid * 32;
        #pragma unroll
        for (int mt=0;mt<2;++mt) {
            const int nb = n0 + mt*16 + hi*4;
            float4 bias = *(const float4*)&b1[nb];
            const float* bp = (const float*)&bias;
            #pragma unroll
            for (int rg=0;rg<8;++rg) {
                const float* a = (const float*)&acc1[mt][rg];
                float y0 = fmaxf(a[0]+bp[0], 0.f), y1 = fmaxf(a[1]+bp[1], 0.f);
                float y2 = fmaxf(a[2]+bp[2], 0.f), y3 = fmaxf(a[3]+bp[3], 0.f);
                *(uint2*)h1p(buf, rg*16+lo, nb) = pack4bf(y0,y1,y2,y3);
            }
        }
    }
    __syncthreads();          // h1 ready

    // ---- GEMM2: rho^T = W21 x h1^T (Nout=128, K=512); wave = (ntile, row-half) ----
    short8 a3p[2];
    f32x4 acc2[4];
    const int nt2 = wid >> 1;         // 0..7
    const int rh  = wid & 1;          // row half
    {
        #pragma unroll
        for (int i=0;i<4;++i) acc2[i]=(f32x4)(0.f);
        #pragma unroll 4
        for (int ks=0; ks<16; ++ks) {
            const int kb = ks*32 + hi*8;
            short8 a = (ks == 0) ? a2p
                     : *(const short8*)&sw21[(nt2*16 + ks)*512 + lane*8];
            #pragma unroll
            for (int i=0;i<4;++i) {
                short8 bf = *(const short8*)h1p(buf, (rh*4+i)*16+lo, kb);
                acc2[i] = __builtin_amdgcn_mfma_f32_16x16x32_bf16(a, bf, acc2[i], 0,0,0);
            }
        }
    }
    __syncthreads();          // h1 reads complete -> reuse buf as xcs

    {
        #pragma unroll
        for (int mt=0;mt<2;++mt)
            a3p[mt] = *(const short8*)&sw3[((wid*2+mt)*8 + 0)*512 + lane*8];
        const int nb = nt2*16 + hi*4;
        float4 bias = *(const float4*)&b21[nb];
        const float* bp = (const float*)&bias;
        #pragma unroll
        for (int i=0;i<4;++i) {
            const float* a = (const float*)&acc2[i];
            *(uint2*)xcp(buf, (rh*4+i)*16+lo, nb) =
                pack4bf(a[0]+bp[0], a[1]+bp[1], a[2]+bp[2], a[3]+bp[3]);
        }
        // xcat[:,128:256] = c2[b]
        int row = tid >> 3, seg = tid & 7;
        const float* src = c2 + b*128 + seg*16;
        #pragma unroll
        for (int i=0;i<4;++i) {
            float4 v = *(const float4*)&src[i*4];
            *(uint2*)xcp(buf, row, 128 + seg*16 + i*4) = pack4bf(v.x, v.y, v.z, v.w);
        }
    }
    __syncthreads();          // xcs ready

    // ---- GEMM3: h3^T = FW1 x xcat^T (Nout=512, K=256) + fused dual dot ----
    float sm[8], sv[8];
    {
        const int n0 = wid * 32;
        f32x4 acc[2][8];
        #pragma unroll
        for (int mt=0;mt<2;++mt)
            #pragma unroll
            for (int rg=0;rg<8;++rg) acc[mt][rg]=(f32x4)(0.f);
        #pragma unroll 2
        for (int ks=0; ks<8; ++ks) {
            const int kb = ks*32 + hi*8;
            short8 af[2];
            if (ks == 0) { af[0]=a3p[0]; af[1]=a3p[1]; }
            else {
                #pragma unroll
                for (int mt=0;mt<2;++mt)
                    af[mt] = *(const short8*)&sw3[((wid*2+mt)*8 + ks)*512 + lane*8];
            }
            #pragma unroll
            for (int rg=0;rg<8;++rg) {
                short8 bf = *(const short8*)xcp(buf, rg*16+lo, kb);
                acc[0][rg] = __builtin_amdgcn_mfma_f32_16x16x32_bf16(af[0], bf, acc[0][rg], 0,0,0);
                acc[1][rg] = __builtin_amdgcn_mfma_f32_16x16x32_bf16(af[1], bf, acc[1][rg], 0,0,0);
            }
        }
        #pragma unroll
        for (int rg=0;rg<8;++rg){ sm[rg]=0.f; sv[rg]=0.f; }
        #pragma unroll
        for (int mt=0;mt<2;++mt) {
            const int nb = n0 + mt*16 + hi*4;
            float4 bias = *(const float4*)&fb1[nb];
            float4 wm   = *(const float4*)&fw21[nb];
            float4 wv   = *(const float4*)&fw22[nb];
            const float *bp=(const float*)&bias, *wmp=(const float*)&wm, *wvp=(const float*)&wv;
            #pragma unroll
            for (int rg=0;rg<8;++rg) {
                const float* a = (const float*)&acc[mt][rg];
                #pragma unroll
                for (int j=0;j<4;++j) {
                    float y = fmaxf(a[j]+bp[j], 0.f);
                    sm[rg] += y*wmp[j];
                    sv[rg] += y*wvp[j];
                }
            }
        }
        #pragma unroll
        for (int rg=0;rg<8;++rg) {
            sm[rg] += __shfl_xor(sm[rg], 16, 64); sm[rg] += __shfl_xor(sm[rg], 32, 64);
            sv[rg] += __shfl_xor(sv[rg], 16, 64); sv[rg] += __shfl_xor(sv[rg], 32, 64);
        }
    }
    __syncthreads();          // xcs reads complete -> reuse buf as pmv
    if (hi == 0) {
        #pragma unroll
        for (int rg=0;rg<8;++rg) {
            pmv[wid*128 + rg*16 + lo]        = sm[rg];
            pmv[2048 + wid*128 + rg*16 + lo] = sv[rg];
        }
    }
    __syncthreads();

    // ---- fused final reduction (one trajectory = this block) ----
    float rl = 0.f, am = 0.f, av = 0.f;
    if (tid < 128) {
        float s_m = 0.f, s_v = 0.f;
        #pragma unroll
        for (int w=0; w<16; ++w) {
            s_m += pmv[w*128 + tid];
            s_v += pmv[2048 + w*128 + tid];
        }
        s_m += fb21[0]; s_v += fb22[0];
        int gi = r0 + tid;
        rl = lengths[roads[gi]] * ratios[gi];
        float ws = rl;
        #pragma unroll
        for (int off=32; off; off>>=1) ws += __shfl_xor(ws, off, 64);
        if (lane == 0) fin[wid] = ws;          // wid 0,1
        am = s_m; av = s_v;                    // stash; lw added after l known
    }
    __syncthreads();
    if (tid < 128) {
        float l = fin[0] + fin[1];
        float logl = logf(l);
        float lw = logf(rl) - logl;
        am += lw; av += 2.f*lw;
        fin[16] = logl;                        // any lane; same value not needed—store from lane0 below
        float mm = am, mv = av;
        #pragma unroll
        for (int off=32; off; off>>=1) { mm = fmaxf(mm, __shfl_xor(mm, off, 64)); mv = fmaxf(mv, __shfl_xor(mv, off, 64)); }
        if (lane == 0) { fin[2+wid] = mm; fin[4+wid] = mv; fin[8+wid] = logl; }
    }
    __syncthreads();
    if (tid < 128) {
        float mm = fmaxf(fin[2], fin[3]);
        float mv = fmaxf(fin[4], fin[5]);
        float se = expf(am - mm), sev = expf(av - mv);
        #pragma unroll
        for (int off=32; off; off>>=1) { se += __shfl_xor(se, off, 64); sev += __shfl_xor(sev, off, 64); }
        if (lane == 0) { fin[10+wid] = se; fin[12+wid] = sev; }
    }
    __syncthreads();
    if (tid == 0) {
        float mm = fmaxf(fin[2], fin[3]);
        float mv = fmaxf(fin[4], fin[5]);
        float lsem = logf(fin[10] + fin[11]) + mm;
        float lsev = logf(fin[12] + fin[13]) + mv;
        float logl = fin[8];
        out[b]       = logl - lsem;
        out[512 + b] = logl - 3.f*lsem - lsev;
    }
}

extern "C" void kernel_launch(void* const* d_in, const int* in_sizes, int n_in,
                              void* d_out, int out_size, void* d_ws, size_t ws_size,
                              hipStream_t stream) {
    const int*   roads   = (const int*)  d_in[0];
    const float* ratios  = (const float*)d_in[1];
    const float* T       = (const float*)d_in[2];
    const int*   lon_idx = (const int*)  d_in[3];
    const int*   lat_idx = (const int*)  d_in[4];
    const float* lengths = (const float*)d_in[5];
    const int*   map_u   = (const int*)  d_in[6];
    const int*   map_s1  = (const int*)  d_in[7];
    const int*   map_s2  = (const int*)  d_in[8];
    const int*   map_s3  = (const int*)  d_in[9];
    const float* emb_u   = (const float*)d_in[10];
    const float* emb_s1  = (const float*)d_in[11];
    const float* emb_s2  = (const float*)d_in[12];
    const float* emb_s3  = (const float*)d_in[13];
    const float* rho_w1  = (const float*)d_in[14];
    const float* rho_b1  = (const float*)d_in[15];
    const float* rho_w21 = (const float*)d_in[16];
    const float* rho_b21 = (const float*)d_in[17];
    const float* conv1_w = (const float*)d_in[18];
    const float* conv1_b = (const float*)d_in[19];
    const float* bn1_g   = (const float*)d_in[20];
    const float* bn1_b   = (const float*)d_in[21];
    const float* conv2_w = (const float*)d_in[22];
    const float* conv2_b = (const float*)d_in[23];
    const float* bn2_g   = (const float*)d_in[24];
    const float* bn2_b   = (const float*)d_in[25];
    const float* conv3_w = (const float*)d_in[26];
    const float* conv3_b = (const float*)d_in[27];
    const float* bn3_g   = (const float*)d_in[28];
    const float* bn3_b   = (const float*)d_in[29];
    const float* f2_w1   = (const float*)d_in[30];
    const float* f2_b1   = (const float*)d_in[31];
    const float* f2_w2   = (const float*)d_in[32];
    const float* f2_b2   = (const float*)d_in[33];
    const float* f_w1    = (const float*)d_in[34];
    const float* f_b1    = (const float*)d_in[35];
    const float* f_w21   = (const float*)d_in[36];
    const float* f_b21   = (const float*)d_in[37];
    const float* f_w22   = (const float*)d_in[38];
    const float* f_b22   = (const float*)d_in[39];

    float* ws    = (float*)d_ws;
    float* t1    = ws;              // [4624][32]  channels-last
    float* t2    = t1 + 147968;     // [1156][64]  channels-last
    float* t3T   = t2 + 73984;      // [289][128]
    float* c2b   = t3T + 36992;
    float* w2t   = c2b + 65536;     // 32768
    float* w3t   = w2t + 32768;     // 131072
    unsigned short* sw1  = (unsigned short*)(w3t + 131072);  // 81920
    unsigned short* sw21 = sw1 + 81920;                      // 65536
    unsigned short* sw3  = sw21 + 65536;                     // 131072

    combo1_kernel<<<PREP_BLOCKS + CONV1_BLOCKS, 256, 0, stream>>>(
        rho_w1, rho_w21, f_w1, sw1, sw21, sw3,
        conv2_w, conv3_w, w2t, w3t,
        T, conv1_w, conv1_b, bn1_g, bn1_b, t1);
    conv2_kernel<<<(64*34*34*4 + 255)/256, 256, 0, stream>>>(t1, w2t, conv2_b, bn2_g, bn2_b, t2);
    conv3_kernel<<<(128*289*8 + 255)/256, 256, 0, stream>>>(t2, w3t, conv3_b, bn3_g, bn3_b, t3T);
    cmh2c2_kernel<<<512, 256, 0, stream>>>(t3T, lat_idx, lon_idx, f2_w1, f2_b1, f2_w2, f2_b2, c2b);
    mega_kernel<<<NBLKG, 1024, 0, stream>>>(roads, ratios, lengths,
                                            map_u, map_s1, map_s2, map_s3,
                                            emb_u, emb_s1, emb_s2, emb_s3,
                                            sw1, rho_b1, sw21, rho_b21,
                                            c2b, sw3, f_b1, f_w21, f_b21, f_w22, f_b22,
                                            (float*)d_out);
}

// Round 7
// 117.106 us; speedup vs baseline: 8.2079x; 1.0006x over previous
//
#include <hip/hip_runtime.h>
#include <hip/hip_bf16.h>
#include <math.h>

#define BB 512
#define SS 128
#define NROWS (BB*SS)      // 65536
#define TMG 128            // rows per mega block = one trajectory
#define NBLKG (NROWS/TMG)  // 512

__device__ __forceinline__ float leaky01(float x){ return x >= 0.f ? x : 0.1f*x; }

#define BN_INV 0.9999950000374997f
#define SELU_A 1.6732632423543772f
#define SELU_S 1.0507009873554805f

typedef __attribute__((ext_vector_type(8))) short short8;
typedef __attribute__((ext_vector_type(4))) float f32x4;

__device__ __forceinline__ unsigned short f2bf(float f) {
    unsigned int u = __float_as_uint(f);
    u += 0x7fff + ((u >> 16) & 1);          // round-to-nearest-even
    return (unsigned short)(u >> 16);
}
// packed cvt: compiler emits v_cvt_pk_bf16_f32 (RNE)
__device__ __forceinline__ unsigned int pk2(float a, float b) {
    __hip_bfloat162 h = __float22bfloat162_rn(make_float2(a, b));
    unsigned int u;
    __builtin_memcpy(&u, &h, 4);
    return u;
}
__device__ __forceinline__ uint2 pack4bf(float a, float b, float c, float d) {
    uint2 r; r.x = pk2(a, b); r.y = pk2(c, d); return r;
}

// LDS tiles, row strides multiple of 128B + XOR swizzle (row&7)<<4.
__device__ __forceinline__ unsigned short* xsp(unsigned short* base, int row, int col) {
    unsigned off = (unsigned)(row*384 + col*2);   // [128][192]
    off ^= (unsigned)((row & 7) << 4);
    return (unsigned short*)((char*)base + off);
}
__device__ __forceinline__ unsigned short* h1p(unsigned short* base, int row, int col) {
    unsigned off = (unsigned)(row*1024 + col*2);  // [128][512]
    off ^= (unsigned)((row & 7) << 4);
    return (unsigned short*)((char*)base + off);
}
__device__ __forceinline__ unsigned short* xcp(unsigned short* base, int row, int col) {
    unsigned off = (unsigned)(row*256 + col*2);   // [128][128]
    off ^= (unsigned)((row & 7) << 4);
    return (unsigned short*)((char*)base + off);
}

// ================= combo: weight swizzle-prep + conv1 =================
#define PREP_N (278528 + 32768 + 131072)   // 442368
#define PREP_BLOCKS (PREP_N/256)           // 1728
#define CONV1_BLOCKS 578                   // ceil(147968/256)

__global__ __launch_bounds__(256) void combo1_kernel(
    const float* __restrict__ w1, const float* __restrict__ w21, const float* __restrict__ fw1,
    unsigned short* __restrict__ sw1, unsigned short* __restrict__ sw21, unsigned short* __restrict__ sw3,
    const float* __restrict__ c2w_in, const float* __restrict__ c3w_in,
    float* __restrict__ w2t, float* __restrict__ w3t,
    const float* __restrict__ T, const float* __restrict__ cw,
    const float* __restrict__ cbias, const float* __restrict__ g,
    const float* __restrict__ bb, float* __restrict__ out)   // out: t1 channels-last [pos68][32]
{
    if (blockIdx.x < PREP_BLOCKS) {
        int t = blockIdx.x*256 + threadIdx.x;
        if (t < 81920) {                       // sw1: 32 ntiles x 5 ks   (w1 [156][512], pad->160)
            int j = t & 7; int r = t >> 3; int lane = r & 63; r >>= 6;
            int ks = r % 5; int nt = r / 5;
            int n = nt*16 + (lane & 15);
            int k = ks*32 + (lane >> 4)*8 + j;
            float v = (k < 156) ? w1[k*512 + n] : 0.f;
            sw1[t] = f2bf(v);
        } else if (t < 147456) {               // sw21: 8 ntiles x 16 ks  (w21 [512][128])
            int u = t - 81920;
            int j = u & 7; int r = u >> 3; int lane = r & 63; r >>= 6;
            int ks = r & 15; int nt = r >> 4;
            int d = nt*16 + (lane & 15);
            int k = ks*32 + (lane >> 4)*8 + j;
            sw21[u] = f2bf(w21[k*128 + d]);
        } else if (t < 278528) {               // sw3: 32 ntiles x 8 ks   (fw1 [256][512])
            int u = t - 147456;
            int j = u & 7; int r = u >> 3; int lane = r & 63; r >>= 6;
            int ks = r & 7; int nt = r >> 3;
            int n = nt*16 + (lane & 15);
            int k = ks*32 + (lane >> 4)*8 + j;
            sw3[u] = f2bf(fw1[k*512 + n]);
        } else if (t < 278528 + 32768) {       // w2t[oc][kk][ic]
            int u = t - 278528;
            int oc = u >> 9; int r = u & 511;
            int kk = r >> 5; int ic = r & 31;
            w2t[u] = c2w_in[oc*512 + ic*16 + kk];
        } else {                               // w3t[oc][kk][ic]
            int u = t - (278528 + 32768);
            int oc = u >> 10; int r = u & 1023;
            int kk = r >> 6; int ic = r & 63;
            w3t[u] = c3w_in[oc*1024 + ic*16 + kk];
        }
    } else {
        int t = (blockIdx.x - PREP_BLOCKS)*256 + threadIdx.x;
        if (t >= 32*68*68) return;
        int oc  = t & 31;
        int pos = t >> 5;
        int oy = pos / 68, ox = pos % 68;
        float acc = cbias[oc];
        #pragma unroll
        for (int ky=0; ky<5; ++ky) {
            int iy = oy*2 - 1 + ky;
            if (iy < 0 || iy >= 138) continue;
            #pragma unroll
            for (int kx=0; kx<5; ++kx) {
                int ix = ox*2 - 1 + kx;
                if (ix < 0 || ix >= 138) continue;
                acc += cw[oc*25 + ky*5 + kx] * T[iy*138 + ix];
            }
        }
        acc = acc * (g[oc]*BN_INV) + bb[oc];
        out[pos*32 + oc] = leaky01(acc);
    }
}

// ================= conv2: channels-last, 4 lanes per output (8 ic each) =================
__global__ __launch_bounds__(256) void conv2_kernel(
    const float* __restrict__ in,      // [pos68][32]
    const float* __restrict__ w2t,     // [oc][kk][ic32]
    const float* __restrict__ bias, const float* __restrict__ g,
    const float* __restrict__ bb, float* __restrict__ out)   // [pos34][64]
{
    int gid = blockIdx.x*256 + threadIdx.x;
    if (gid >= 64*34*34*4) return;
    int icg = gid & 3;
    int o   = gid >> 2;
    int oc  = o & 63;
    int pos = o >> 6;
    int oy = pos / 34, ox = pos % 34;
    float acc = 0.f;
    #pragma unroll
    for (int ky=0; ky<4; ++ky) {
        int iy = oy*2 - 1 + ky;
        if (iy < 0 || iy >= 68) continue;
        #pragma unroll
        for (int kx=0; kx<4; ++kx) {
            int ix = ox*2 - 1 + kx;
            if (ix < 0 || ix >= 68) continue;
            const float* ip = &in[(iy*68+ix)*32 + icg*8];
            const float* wp = &w2t[oc*512 + (ky*4+kx)*32 + icg*8];
            float4 i0 = *(const float4*)ip, i1 = *(const float4*)(ip+4);
            float4 w0 = *(const float4*)wp, w1v = *(const float4*)(wp+4);
            acc += i0.x*w0.x + i0.y*w0.y + i0.z*w0.z + i0.w*w0.w
                 + i1.x*w1v.x + i1.y*w1v.y + i1.z*w1v.z + i1.w*w1v.w;
        }
    }
    acc += __shfl_xor(acc, 1, 64);
    acc += __shfl_xor(acc, 2, 64);
    if (icg == 0) {
        acc = (acc + bias[oc]) * (g[oc]*BN_INV) + bb[oc];
        out[pos*64 + oc] = leaky01(acc);
    }
}

// ================= conv3: channels-last, 8 lanes per output, transposed out =================
__global__ __launch_bounds__(256) void conv3_kernel(
    const float* __restrict__ in,      // [pos34][64]
    const float* __restrict__ w3t,     // [oc][kk][ic64]
    const float* __restrict__ bias, const float* __restrict__ g,
    const float* __restrict__ bb, float* __restrict__ outT)  // [pos17][128]
{
    int gid = blockIdx.x*256 + threadIdx.x;
    if (gid >= 128*289*8) return;
    int icg = gid & 7;
    int o   = gid >> 3;
    int oc  = o & 127;
    int pos = o >> 7;
    int oy = pos / 17, ox = pos % 17;
    float acc = 0.f;
    #pragma unroll
    for (int ky=0; ky<4; ++ky) {
        int iy = oy*2 - 1 + ky;
        if (iy < 0 || iy >= 34) continue;
        #pragma unroll
        for (int kx=0; kx<4; ++kx) {
            int ix = ox*2 - 1 + kx;
            if (ix < 0 || ix >= 34) continue;
            const float* ip = &in[(iy*34+ix)*64 + icg*8];
            const float* wp = &w3t[oc*1024 + (ky*4+kx)*64 + icg*8];
            float4 i0 = *(const float4*)ip, i1 = *(const float4*)(ip+4);
            float4 w0 = *(const float4*)wp, w1v = *(const float4*)(wp+4);
            acc += i0.x*w0.x + i0.y*w0.y + i0.z*w0.z + i0.w*w0.w
                 + i1.x*w1v.x + i1.y*w1v.y + i1.z*w1v.z + i1.w*w1v.w;
        }
    }
    acc += __shfl_xor(acc, 1, 64);
    acc += __shfl_xor(acc, 2, 64);
    acc += __shfl_xor(acc, 4, 64);
    if (icg == 0) {
        acc = (acc + bias[oc]) * (g[oc]*BN_INV) + bb[oc];
        outT[pos*128 + oc] = leaky01(acc);
    }
}

// ===== fused cmean -> h2(selu) -> c2 -> cv[b] = c2 @ FW1[128:256] + fb1, one block per b =====
__global__ __launch_bounds__(256) void cmh2c2_kernel(
    const float* __restrict__ t3T, const int* __restrict__ lat, const int* __restrict__ lon,
    const float* __restrict__ w1, const float* __restrict__ b1,
    const float* __restrict__ w2, const float* __restrict__ b2,
    const float* __restrict__ fw1, const float* __restrict__ fb1,
    float* __restrict__ cvb)
{
    __shared__ int   ps[64];
    __shared__ float part[256];
    __shared__ float cms[128];
    __shared__ float h2s[256];
    __shared__ float c2s[128];
    const int b = blockIdx.x;
    const int tid = threadIdx.x;
    if (tid < 64) ps[tid] = lat[b*64+tid]*17 + lon[b*64+tid];
    __syncthreads();
    {
        int d = tid & 127, half = tid >> 7;
        float s = 0.f;
        #pragma unroll 8
        for (int k=0; k<32; ++k) s += t3T[ps[half*32+k]*128 + d];
        part[tid] = s;
    }
    __syncthreads();
    if (tid < 128) cms[tid] = (part[tid] + part[tid+128]) * (1.f/64.f);
    __syncthreads();
    {
        float acc = b1[tid];
        #pragma unroll 8
        for (int k=0; k<128; ++k) acc += cms[k] * w1[k*256 + tid];
        h2s[tid] = acc > 0.f ? SELU_S*acc : SELU_S*SELU_A*(expf(acc)-1.f);
    }
    __syncthreads();
    {
        int d = tid & 127, half = tid >> 7;
        float acc = 0.f;
        #pragma unroll 8
        for (int k=0; k<128; ++k) acc += h2s[half*128 + k] * w2[(half*128+k)*128 + d];
        part[tid] = acc;
    }
    __syncthreads();
    if (tid < 128) c2s[tid] = part[tid] + part[tid+128] + b2[tid];
    __syncthreads();
    // cv[n] = fb1[n] + sum_k c2[k] * fw1[(128+k)*512 + n]   (fp32, exact)
    {
        float a0 = fb1[tid], a1 = fb1[tid + 256];
        #pragma unroll 8
        for (int k=0; k<128; ++k) {
            float c = c2s[k];
            a0 += c * fw1[(128+k)*512 + tid];
            a1 += c * fw1[(128+k)*512 + 256 + tid];
        }
        cvb[b*512 + tid]       = a0;
        cvb[b*512 + 256 + tid] = a1;
    }
}

// ================= mega: 128 rows (one trajectory) per block, 16 waves =================
// 128KB LDS buf aliased: xs[128][192] -> h1[128][512] -> xcs[128][128] -> pmv + fin
__global__ __launch_bounds__(1024, 4) void mega_kernel(
    const int* __restrict__ roads, const float* __restrict__ ratios,
    const float* __restrict__ lengths,
    const int* __restrict__ map_u, const int* __restrict__ map_s1,
    const int* __restrict__ map_s2, const int* __restrict__ map_s3,
    const float* __restrict__ emb_u, const float* __restrict__ emb_s1,
    const float* __restrict__ emb_s2, const float* __restrict__ emb_s3,
    const unsigned short* __restrict__ sw1, const float* __restrict__ b1,
    const unsigned short* __restrict__ sw21, const float* __restrict__ b21,
    const unsigned short* __restrict__ sw3, const float* __restrict__ cvb,
    const float* __restrict__ fw21, const float* __restrict__ fb21,
    const float* __restrict__ fw22, const float* __restrict__ fb22,
    float* __restrict__ out)
{
    __shared__ unsigned short buf[65536];     // 131072 B
    float* pmv = (float*)buf;                 // pm[16][128] | pv[16][128]  (16 KB)
    float* fin = (float*)buf + 4096;          // final-phase scratch

    const int tid  = threadIdx.x;
    const int wid  = tid >> 6;                // 0..15
    const int lane = tid & 63;
    const int lo   = lane & 15;
    const int hi   = lane >> 4;
    const int b    = blockIdx.x;
    const int r0   = b * TMG;
    const int nt2  = wid >> 1;                // GEMM2 ntile
    const int rh   = wid & 1;                 // GEMM2 row half

    // ---- prefetch GEMM1 ks=0,1 A-fragments ----
    short8 afp00 = *(const short8*)&sw1[((wid*2+0)*5 + 0)*512 + lane*8];
    short8 afp10 = *(const short8*)&sw1[((wid*2+1)*5 + 0)*512 + lane*8];
    short8 afp01 = *(const short8*)&sw1[((wid*2+0)*5 + 1)*512 + lane*8];
    short8 afp11 = *(const short8*)&sw1[((wid*2+1)*5 + 1)*512 + lane*8];

    // ---- gather x rows into xs [128][192] (swizzled) ----
    {
        int row = tid >> 3, seg = tid & 7;
        int road = roads[r0 + row];
        const float* src = emb_u + (long)map_u[road]*128 + seg*16;
        #pragma unroll
        for (int i=0;i<4;++i) {
            float4 v = *(const float4*)&src[i*4];
            *(uint2*)xsp(buf, row, seg*16 + i*4) = pack4bf(v.x, v.y, v.z, v.w);
        }
    }
    for (int idx = tid; idx < 128*32; idx += 1024) {
        int row = idx >> 5, k2 = idx & 31;
        int road = roads[r0 + row];
        float v;
        if      (k2 < 16) v = emb_s1[map_s1[road]*16 + k2];
        else if (k2 < 24) v = emb_s2[map_s2[road]*8  + (k2-16)];
        else if (k2 < 28) v = emb_s3[map_s3[road]*4  + (k2-24)];
        else              v = 0.f;
        *xsp(buf, row, 128 + k2) = f2bf(v);
    }
    __syncthreads();

    // ---- GEMM1: h1^T = W1 x X^T (Nout=512, K=160); af 2-ahead, bf batched ----
    f32x4 acc1[2][8];
    {
        #pragma unroll
        for (int mt=0;mt<2;++mt)
            #pragma unroll
            for (int rg=0;rg<8;++rg) acc1[mt][rg]=(f32x4)(0.f);
        short8 a0c = afp00, a1c = afp10, a0n = afp01, a1n = afp11;
        #pragma unroll
        for (int ks=0; ks<5; ++ks) {
            short8 a0f = a0c, a1f = a1c;
            if (ks < 3) {
                a0f = *(const short8*)&sw1[((wid*2+0)*5 + ks+2)*512 + lane*8];
                a1f = *(const short8*)&sw1[((wid*2+1)*5 + ks+2)*512 + lane*8];
            }
            const int kb = ks*32 + hi*8;
            short8 bf[4];
            #pragma unroll
            for (int rg=0;rg<4;++rg) bf[rg] = *(const short8*)xsp(buf, rg*16+lo, kb);
            #pragma unroll
            for (int rg=0;rg<4;++rg) {
                acc1[0][rg] = __builtin_amdgcn_mfma_f32_16x16x32_bf16(a0c, bf[rg], acc1[0][rg], 0,0,0);
                acc1[1][rg] = __builtin_amdgcn_mfma_f32_16x16x32_bf16(a1c, bf[rg], acc1[1][rg], 0,0,0);
            }
            #pragma unroll
            for (int rg=0;rg<4;++rg) bf[rg] = *(const short8*)xsp(buf, (4+rg)*16+lo, kb);
            #pragma unroll
            for (int rg=0;rg<4;++rg) {
                acc1[0][4+rg] = __builtin_amdgcn_mfma_f32_16x16x32_bf16(a0c, bf[rg], acc1[0][4+rg], 0,0,0);
                acc1[1][4+rg] = __builtin_amdgcn_mfma_f32_16x16x32_bf16(a1c, bf[rg], acc1[1][4+rg], 0,0,0);
            }
            a0c = a0n; a1c = a1n; a0n = a0f; a1n = a1f;
        }
    }
    __syncthreads();          // xs reads complete -> reuse buf as h1

    // ---- epi1: h1 writes; prefetch GEMM2 ks=0..3 ----
    short8 a2q0, a2q1, a2q2, a2q3;
    {
        a2q0 = *(const short8*)&sw21[(nt2*16 + 0)*512 + lane*8];
        a2q1 = *(const short8*)&sw21[(nt2*16 + 1)*512 + lane*8];
        a2q2 = *(const short8*)&sw21[(nt2*16 + 2)*512 + lane*8];
        a2q3 = *(const short8*)&sw21[(nt2*16 + 3)*512 + lane*8];
        const int n0 = wid * 32;
        #pragma unroll
        for (int mt=0;mt<2;++mt) {
            const int nb = n0 + mt*16 + hi*4;
            float4 bias = *(const float4*)&b1[nb];
            const float* bp = (const float*)&bias;
            #pragma unroll
            for (int rg=0;rg<8;++rg) {
                const float* a = (const float*)&acc1[mt][rg];
                float y0 = fmaxf(a[0]+bp[0], 0.f), y1 = fmaxf(a[1]+bp[1], 0.f);
                float y2 = fmaxf(a[2]+bp[2], 0.f), y3 = fmaxf(a[3]+bp[3], 0.f);
                *(uint2*)h1p(buf, rg*16+lo, nb) = pack4bf(y0,y1,y2,y3);
            }
        }
    }
    __syncthreads();          // h1 ready

    // ---- GEMM2: rho^T = W21 x h1^T (Nout=128, K=512); af 4-deep rotate ----
    f32x4 acc2[4];
    {
        #pragma unroll
        for (int i=0;i<4;++i) acc2[i]=(f32x4)(0.f);
        #pragma unroll
        for (int ks=0; ks<16; ++ks) {
            short8 a_use = a2q0;
            a2q0 = a2q1; a2q1 = a2q2; a2q2 = a2q3;
            if (ks < 12)
                a2q3 = *(const short8*)&sw21[(nt2*16 + ks+4)*512 + lane*8];
            const int kb = ks*32 + hi*8;
            short8 bf[4];
            #pragma unroll
            for (int i=0;i<4;++i) bf[i] = *(const short8*)h1p(buf, (rh*4+i)*16+lo, kb);
            #pragma unroll
            for (int i=0;i<4;++i)
                acc2[i] = __builtin_amdgcn_mfma_f32_16x16x32_bf16(a_use, bf[i], acc2[i], 0,0,0);
        }
    }
    __syncthreads();          // h1 reads complete -> reuse buf as xcs

    // ---- epi2: write rho to xcs [128][128]; prefetch GEMM3 ks=0,1 ----
    short8 a3c0, a3c1, a3n0, a3n1;
    {
        a3c0 = *(const short8*)&sw3[((wid*2+0)*8 + 0)*512 + lane*8];
        a3c1 = *(const short8*)&sw3[((wid*2+1)*8 + 0)*512 + lane*8];
        a3n0 = *(const short8*)&sw3[((wid*2+0)*8 + 1)*512 + lane*8];
        a3n1 = *(const short8*)&sw3[((wid*2+1)*8 + 1)*512 + lane*8];
        const int nb = nt2*16 + hi*4;
        float4 bias = *(const float4*)&b21[nb];
        const float* bp = (const float*)&bias;
        #pragma unroll
        for (int i=0;i<4;++i) {
            const float* a = (const float*)&acc2[i];
            *(uint2*)xcp(buf, (rh*4+i)*16+lo, nb) =
                pack4bf(a[0]+bp[0], a[1]+bp[1], a[2]+bp[2], a[3]+bp[3]);
        }
    }
    __syncthreads();          // xcs ready

    // ---- GEMM3: h3^T = FW1a x rho^T (Nout=512, K=128) + cv bias + fused dual dot ----
    float sm[8], sv[8];
    {
        const int n0 = wid * 32;
        f32x4 acc[2][8];
        #pragma unroll
        for (int mt=0;mt<2;++mt)
            #pragma unroll
            for (int rg=0;rg<8;++rg) acc[mt][rg]=(f32x4)(0.f);
        #pragma unroll
        for (int ks=0; ks<4; ++ks) {
            short8 c0f = a3c0, c1f = a3c1;
            if (ks < 2) {
                c0f = *(const short8*)&sw3[((wid*2+0)*8 + ks+2)*512 + lane*8];
                c1f = *(const short8*)&sw3[((wid*2+1)*8 + ks+2)*512 + lane*8];
            }
            const int kb = ks*32 + hi*8;
            short8 bf[4];
            #pragma unroll
            for (int rg=0;rg<4;++rg) bf[rg] = *(const short8*)xcp(buf, rg*16+lo, kb);
            #pragma unroll
            for (int rg=0;rg<4;++rg) {
                acc[0][rg] = __builtin_amdgcn_mfma_f32_16x16x32_bf16(a3c0, bf[rg], acc[0][rg], 0,0,0);
                acc[1][rg] = __builtin_amdgcn_mfma_f32_16x16x32_bf16(a3c1, bf[rg], acc[1][rg], 0,0,0);
            }
            #pragma unroll
            for (int rg=0;rg<4;++rg) bf[rg] = *(const short8*)xcp(buf, (4+rg)*16+lo, kb);
            #pragma unroll
            for (int rg=0;rg<4;++rg) {
                acc[0][4+rg] = __builtin_amdgcn_mfma_f32_16x16x32_bf16(a3c0, bf[rg], acc[0][4+rg], 0,0,0);
                acc[1][4+rg] = __builtin_amdgcn_mfma_f32_16x16x32_bf16(a3c1, bf[rg], acc[1][4+rg], 0,0,0);
            }
            a3c0 = a3n0; a3c1 = a3n1; a3n0 = c0f; a3n1 = c1f;
        }
        #pragma unroll
        for (int rg=0;rg<8;++rg){ sm[rg]=0.f; sv[rg]=0.f; }
        #pragma unroll
        for (int mt=0;mt<2;++mt) {
            const int nb = n0 + mt*16 + hi*4;
            float4 bias = *(const float4*)&cvb[b*512 + nb];   // includes fb1 + c2@FW1b
            float4 wm   = *(const float4*)&fw21[nb];
            float4 wv   = *(const float4*)&fw22[nb];
            const float *bp=(const float*)&bias, *wmp=(const float*)&wm, *wvp=(const float*)&wv;
            #pragma unroll
            for (int rg=0;rg<8;++rg) {
                const float* a = (const float*)&acc[mt][rg];
                #pragma unroll
                for (int j=0;j<4;++j) {
                    float y = fmaxf(a[j]+bp[j], 0.f);
                    sm[rg] += y*wmp[j];
                    sv[rg] += y*wvp[j];
                }
            }
        }
        #pragma unroll
        for (int rg=0;rg<8;++rg) {
            sm[rg] += __shfl_xor(sm[rg], 16, 64); sm[rg] += __shfl_xor(sm[rg], 32, 64);
            sv[rg] += __shfl_xor(sv[rg], 16, 64); sv[rg] += __shfl_xor(sv[rg], 32, 64);
        }
    }
    __syncthreads();          // xcs reads complete -> reuse buf as pmv
    if (hi == 0) {
        #pragma unroll
        for (int rg=0;rg<8;++rg) {
            pmv[wid*128 + rg*16 + lo]        = sm[rg];
            pmv[2048 + wid*128 + rg*16 + lo] = sv[rg];
        }
    }
    __syncthreads();

    // ---- fused final reduction (one trajectory = this block) ----
    float rl = 0.f, am = 0.f, av = 0.f;
    if (tid < 128) {
        float s_m = 0.f, s_v = 0.f;
        #pragma unroll
        for (int w=0; w<16; ++w) {
            s_m += pmv[w*128 + tid];
            s_v += pmv[2048 + w*128 + tid];
        }
        s_m += fb21[0]; s_v += fb22[0];
        int gi = r0 + tid;
        rl = lengths[roads[gi]] * ratios[gi];
        float ws = rl;
        #pragma unroll
        for (int off=32; off; off>>=1) ws += __shfl_xor(ws, off, 64);
        if (lane == 0) fin[wid] = ws;          // wid 0,1
        am = s_m; av = s_v;
    }
    __syncthreads();
    if (tid < 128) {
        float l = fin[0] + fin[1];
        float logl = logf(l);
        float lw = logf(rl) - logl;
        am += lw; av += 2.f*lw;
        float mm = am, mv = av;
        #pragma unroll
        for (int off=32; off; off>>=1) { mm = fmaxf(mm, __shfl_xor(mm, off, 64)); mv = fmaxf(mv, __shfl_xor(mv, off, 64)); }
        if (lane == 0) { fin[2+wid] = mm; fin[4+wid] = mv; fin[8+wid] = logl; }
    }
    __syncthreads();
    if (tid < 128) {
        float mm = fmaxf(fin[2], fin[3]);
        float mv = fmaxf(fin[4], fin[5]);
        float se = expf(am - mm), sev = expf(av - mv);
        #pragma unroll
        for (int off=32; off; off>>=1) { se += __shfl_xor(se, off, 64); sev += __shfl_xor(sev, off, 64); }
        if (lane == 0) { fin[10+wid] = se; fin[12+wid] = sev; }
    }
    __syncthreads();
    if (tid == 0) {
        float mm = fmaxf(fin[2], fin[3]);
        float mv = fmaxf(fin[4], fin[5]);
        float lsem = logf(fin[10] + fin[11]) + mm;
        float lsev = logf(fin[12] + fin[13]) + mv;
        float logl = fin[8];
        out[b]       = logl - lsem;
        out[512 + b] = logl - 3.f*lsem - lsev;
    }
}

extern "C" void kernel_launch(void* const* d_in, const int* in_sizes, int n_in,
                              void* d_out, int out_size, void* d_ws, size_t ws_size,
                              hipStream_t stream) {
    const int*   roads   = (const int*)  d_in[0];
    const float* ratios  = (const float*)d_in[1];
    const float* T       = (const float*)d_in[2];
    const int*   lon_idx = (const int*)  d_in[3];
    const int*   lat_idx = (const int*)  d_in[4];
    const float* lengths = (const float*)d_in[5];
    const int*   map_u   = (const int*)  d_in[6];
    const int*   map_s1  = (const int*)  d_in[7];
    const int*   map_s2  = (const int*)  d_in[8];
    const int*   map_s3  = (const int*)  d_in[9];
    const float* emb_u   = (const float*)d_in[10];
    const float* emb_s1  = (const float*)d_in[11];
    const float* emb_s2  = (const float*)d_in[12];
    const float* emb_s3  = (const float*)d_in[13];
    const float* rho_w1  = (const float*)d_in[14];
    const float* rho_b1  = (const float*)d_in[15];
    const float* rho_w21 = (const float*)d_in[16];
    const float* rho_b21 = (const float*)d_in[17];
    const float* conv1_w = (const float*)d_in[18];
    const float* conv1_b = (const float*)d_in[19];
    const float* bn1_g   = (const float*)d_in[20];
    const float* bn1_b   = (const float*)d_in[21];
    const float* conv2_w = (const float*)d_in[22];
    const float* conv2_b = (const float*)d_in[23];
    const float* bn2_g   = (const float*)d_in[24];
    const float* bn2_b   = (const float*)d_in[25];
    const float* conv3_w = (const float*)d_in[26];
    const float* conv3_b = (const float*)d_in[27];
    const float* bn3_g   = (const float*)d_in[28];
    const float* bn3_b   = (const float*)d_in[29];
    const float* f2_w1   = (const float*)d_in[30];
    const float* f2_b1   = (const float*)d_in[31];
    const float* f2_w2   = (const float*)d_in[32];
    const float* f2_b2   = (const float*)d_in[33];
    const float* f_w1    = (const float*)d_in[34];
    const float* f_b1    = (const float*)d_in[35];
    const float* f_w21   = (const float*)d_in[36];
    const float* f_b21   = (const float*)d_in[37];
    const float* f_w22   = (const float*)d_in[38];
    const float* f_b22   = (const float*)d_in[39];

    float* ws    = (float*)d_ws;
    float* t1    = ws;              // [4624][32]  channels-last
    float* t2    = t1 + 147968;     // [1156][64]  channels-last
    float* t3T   = t2 + 73984;      // [289][128]
    float* cvb   = t3T + 36992;     // [512][512]
    float* w2t   = cvb + 262144;    // 32768
    float* w3t   = w2t + 32768;     // 131072
    unsigned short* sw1  = (unsigned short*)(w3t + 131072);  // 81920
    unsigned short* sw21 = sw1 + 81920;                      // 65536
    unsigned short* sw3  = sw21 + 65536;                     // 131072

    combo1_kernel<<<PREP_BLOCKS + CONV1_BLOCKS, 256, 0, stream>>>(
        rho_w1, rho_w21, f_w1, sw1, sw21, sw3,
        conv2_w, conv3_w, w2t, w3t,
        T, conv1_w, conv1_b, bn1_g, bn1_b, t1);
    conv2_kernel<<<(64*34*34*4 + 255)/256, 256, 0, stream>>>(t1, w2t, conv2_b, bn2_g, bn2_b, t2);
    conv3_kernel<<<(128*289*8 + 255)/256, 256, 0, stream>>>(t2, w3t, conv3_b, bn3_g, bn3_b, t3T);
    cmh2c2_kernel<<<512, 256, 0, stream>>>(t3T, lat_idx, lon_idx, f2_w1, f2_b1, f2_w2, f2_b2,
                                           f_w1, f_b1, cvb);
    mega_kernel<<<NBLKG, 1024, 0, stream>>>(roads, ratios, lengths,
                                            map_u, map_s1, map_s2, map_s3,
                                            emb_u, emb_s1, emb_s2, emb_s3,
                                            sw1, rho_b1, sw21, rho_b21,
                                            sw3, cvb, f_w21, f_b21, f_w22, f_b22,
                                            (float*)d_out);
}